// Round 1
// baseline (1668.192 us; speedup 1.0000x reference)
//
#include <hip/hip_runtime.h>
#include <math.h>

typedef unsigned short u16;
typedef unsigned int   u32;
typedef __attribute__((ext_vector_type(4))) float f32x4;
typedef __attribute__((ext_vector_type(4))) u32   u32x4;

#define DEV __device__ __forceinline__

DEV float b2f(u16 u){ u32 x = ((u32)u)<<16; float f; __builtin_memcpy(&f,&x,4); return f; }
DEV u16 f2b(float f){ u32 x; __builtin_memcpy(&x,&f,4); u32 r = x + 0x7FFFu + ((x>>16)&1u); return (u16)(r>>16); }

DEV float ldf(const float* p, long i){ return p[i]; }
DEV float ldf(const u16*   p, long i){ return b2f(p[i]); }

DEV float wave_sum(float v){
#pragma unroll
  for(int o=32;o;o>>=1) v += __shfl_down(v,o,64);
  return v;
}
DEV float wave_max(float v){
#pragma unroll
  for(int o=32;o;o>>=1) v = fmaxf(v, __shfl_down(v,o,64));
  return v;
}
// blockDim.x == 256 assumed everywhere below.
DEV float block_sum(float v, float* tmp){
  v = wave_sum(v);
  if((threadIdx.x&63)==0) tmp[threadIdx.x>>6]=v;
  __syncthreads();
  float r = tmp[0]+tmp[1]+tmp[2]+tmp[3];
  __syncthreads();
  return r;
}
DEV float block_max(float v, float* tmp){
  v = wave_max(v);
  if((threadIdx.x&63)==0) tmp[threadIdx.x>>6]=v;
  __syncthreads();
  float r = fmaxf(fmaxf(tmp[0],tmp[1]),fmaxf(tmp[2],tmp[3]));
  __syncthreads();
  return r;
}

// ---------------- transpose (+K-pad with zeros), out always bf16 -------------
template<typename TI>
__global__ void transpose_pad(const TI* __restrict__ in, u16* __restrict__ out,
                              int R, int C, int Rpad, long strideI, long strideO){
  __shared__ u16 t[32][33];
  in  += (long)blockIdx.z*strideI;
  out += (long)blockIdx.z*strideO;
  int tx = threadIdx.x & 31, ty = threadIdx.x >> 5;
  int bc = blockIdx.x*32, br = blockIdx.y*32;
#pragma unroll
  for(int i=0;i<32;i+=8){
    int r = br+ty+i, c = bc+tx;
    float v = (r<R && c<C) ? ldf(in,(long)r*C+c) : 0.f;
    t[ty+i][tx] = f2b(v);
  }
  __syncthreads();
#pragma unroll
  for(int i=0;i<32;i+=8){
    int c = bc+ty+i, r = br+tx;
    if(c<C && r<Rpad) out[(long)c*Rpad + r] = t[tx][ty+i];
  }
}

// ---------------- LayerNorm rows ---------------------------------------------
template<typename TI>
__global__ void ln_rows(const TI* __restrict__ x, const float* __restrict__ g,
                        const float* __restrict__ b, u16* __restrict__ y, int W){
  __shared__ float tmp[4];
  long base=(long)blockIdx.x*W;
  float s=0.f, ss=0.f;
  for(int c=threadIdx.x;c<W;c+=256){ float v=ldf(x,base+c); s+=v; ss+=v*v; }
  s=block_sum(s,tmp); ss=block_sum(ss,tmp);
  float mu=s/W;
  float rstd=rsqrtf(fmaxf(ss/W-mu*mu,0.f)+1e-5f);
  for(int c=threadIdx.x;c<W;c+=256){
    float v=ldf(x,base+c);
    y[base+c]=f2b((v-mu)*rstd*g[c]+b[c]);
  }
}

__global__ void row_stats(const u16* __restrict__ x, float* __restrict__ stats, int W){
  __shared__ float tmp[4];
  long base=(long)blockIdx.x*W;
  float s=0.f,ss=0.f;
  for(int c=threadIdx.x;c<W;c+=256){ float v=b2f(x[base+c]); s+=v; ss+=v*v; }
  s=block_sum(s,tmp); ss=block_sum(ss,tmp);
  if(threadIdx.x==0){
    float mu=s/W;
    stats[2*(long)blockIdx.x]=mu;
    stats[2*(long)blockIdx.x+1]=rsqrtf(fmaxf(ss/W-mu*mu,0.f)+1e-5f);
  }
}

// dn = LN(hid; d_ln), rn = 1/max(||dn||,1e-12)
__global__ void dn_kernel(const u16* __restrict__ x, const float* __restrict__ g,
                          const float* __restrict__ b, u16* __restrict__ dn,
                          float* __restrict__ rn){
  const int W=3072;
  __shared__ float tmp[4];
  long base=(long)blockIdx.x*(long)W;
  float s=0.f,ss=0.f;
  for(int c=threadIdx.x;c<W;c+=256){ float v=b2f(x[base+c]); s+=v; ss+=v*v; }
  s=block_sum(s,tmp); ss=block_sum(ss,tmp);
  float mu=s/W;
  float rstd=rsqrtf(fmaxf(ss/W-mu*mu,0.f)+1e-5f);
  float sq=0.f;
  for(int c=threadIdx.x;c<W;c+=256){
    float v=(b2f(x[base+c])-mu)*rstd*g[c]+b[c];
    sq+=v*v;
  }
  sq=block_sum(sq,tmp);
  float r=1.f/fmaxf(sqrtf(sq),1e-12f);
  for(int c=threadIdx.x;c<W;c+=256){
    float v=(b2f(x[base+c])-mu)*rstd*g[c]+b[c];
    dn[base+c]=f2b(v);
  }
  if(threadIdx.x==0) rn[blockIdx.x]=r;
}

// ------------- softmax over rows (in-place bf16), optional row/col scaling ---
__global__ void softmax_rows(u16* __restrict__ S, int W, int Wp,
                             const float* __restrict__ rs, int rpb, float alpha){
  __shared__ float tmp[4];
  long row = blockIdx.x;
  u16* p = S + row*(long)Wp;
  float rowscale = alpha;
  const float* rsb = nullptr;
  if(rs){ long bt=row/rpb; int m=(int)(row%rpb); rsb = rs + bt*(long)rpb; rowscale *= rsb[m]; }
  float mx=-3e38f;
  for(int c=threadIdx.x;c<W;c+=256){
    float v=b2f(p[c])*rowscale; if(rs) v*=rsb[c];
    mx=fmaxf(mx,v);
  }
  mx=block_max(mx,tmp);
  float sm=0.f;
  for(int c=threadIdx.x;c<W;c+=256){
    float v=b2f(p[c])*rowscale; if(rs) v*=rsb[c];
    sm+=__expf(v-mx);
  }
  sm=block_sum(sm,tmp);
  float inv=1.f/sm;
  for(int c=threadIdx.x;c<W;c+=256){
    float v=b2f(p[c])*rowscale; if(rs) v*=rsb[c];
    p[c]=f2b(__expf(v-mx)*inv);
  }
  for(int c=W+threadIdx.x;c<Wp;c+=256) p[c]=0;
}

// ---------------- attention head reshapes ------------------------------------
__global__ void split_heads(const u16* __restrict__ qk, u16* __restrict__ qh, u16* __restrict__ kh){
  int i = blockIdx.x*256+threadIdx.x;
  if(i >= 16*577*12*8) return;
  int dv = i&7; int h=(i>>3)%12; int bn=i/96;
  int b=bn/577, n=bn%577;
  long src=(long)bn*1536 + h*64 + dv*8;
  long dst=((long)((b*12+h)*577+n))*64 + dv*8;
  *(u32x4*)(qh+dst) = *(const u32x4*)(qk+src);
  *(u32x4*)(kh+dst) = *(const u32x4*)(qk+src+768);
}
__global__ void merge_heads(const u16* __restrict__ aoh, u16* __restrict__ aout){
  int i = blockIdx.x*256+threadIdx.x;
  if(i >= 16*577*12*8) return;
  int dv=i&7; int h=(i>>3)%12; int bn=i/96;
  int b=bn/577, n=bn%577;
  long dst=(long)bn*768 + h*64 + dv*8;
  long src=((long)((b*12+h)*577+n))*64 + dv*8;
  *(u32x4*)(aout+dst) = *(const u32x4*)(aoh+src);
}
__global__ void make_vT(const u16* __restrict__ v, u16* __restrict__ vT){
  long i = (long)blockIdx.x*256+threadIdx.x;
  if(i >= (long)192*64*608) return;
  int n=(int)(i%608); long q=i/608; int d=(int)(q&63); int bh=(int)(q>>6);
  int b=bh/12, h=bh%12;
  u16 val=0;
  if(n<577) val = v[((long)(b*577+n))*768 + h*64 + d];
  vT[i]=val;
}

// ---------------- router -----------------------------------------------------
__global__ void summary_kernel(const u16* __restrict__ hid, const float* __restrict__ stats,
                               const float* __restrict__ rg, const float* __restrict__ rb,
                               float* __restrict__ summ){
  int b=blockIdx.y;
  int c=blockIdx.x*256+threadIdx.x;   // grid.x=12 -> c<3072
  const u16* hb=hid+(size_t)b*577*3072;
  const float* st=stats+(size_t)b*577*2;
  float g=rg[c], be=rb[c];
  float cls=(b2f(hb[c])-st[0])*st[1]*g+be;
  float acc=0.f;
  for(int n=1;n<577;n++) acc += (b2f(hb[(size_t)n*3072+c])-st[2*n])*st[2*n+1];
  summ[(size_t)b*6144+c]        = 1.0f*cls;                         // CLS_MIX
  summ[(size_t)b*6144+3072+c]   = 0.5f*(g*(acc*(1.f/576.f))+be);    // MEAN_MIX
}

__global__ void router_kernel(const float* __restrict__ summ, const float* __restrict__ pw,
                              const float* __restrict__ pb, const float* __restrict__ gw,
                              const float* __restrict__ gb, const float* __restrict__ rsc,
                              float* __restrict__ scalef){
  __shared__ float tmp[4];
  int b=blockIdx.x;
  float a0=0,a1=0,a2=0,a3=0,a4=0;
  for(int c=threadIdx.x;c<6144;c+=256){
    float sv=summ[(size_t)b*6144+c];
    a0+=sv*pw[c*4+0]; a1+=sv*pw[c*4+1]; a2+=sv*pw[c*4+2]; a3+=sv*pw[c*4+3];
    a4+=sv*gw[c];
  }
  a0=block_sum(a0,tmp); a1=block_sum(a1,tmp); a2=block_sum(a2,tmp);
  a3=block_sum(a3,tmp); a4=block_sum(a4,tmp);
  if(threadIdx.x==0){
    float l0=a0+pb[0], l1=a1+pb[1], l2=a2+pb[2], l3=a3+pb[3];
    float mx=fmaxf(fmaxf(l0,l1),fmaxf(l2,l3));
    float e0=__expf(l0-mx),e1=__expf(l1-mx),e2=__expf(l2-mx),e3=__expf(l3-mx);
    float s=e0+e1+e2+e3;
    float gate=1.f/(1.f+__expf(-(a4+gb[0])));
    float w0=e0/s,w1=e1/s,w2=e2/s,w3=e3/s;
    scalef[b*4+0]=1.f+gate*rsc[0]*(4.f*w0-1.f);
    scalef[b*4+1]=1.f+gate*rsc[1]*(4.f*w1-1.f);
    scalef[b*4+2]=1.f+gate*rsc[2]*(4.f*w2-1.f);
    scalef[b*4+3]=1.f+gate*rsc[3]*(4.f*w3-1.f);
  }
}

__global__ void scale_hid(u16* __restrict__ hid, const float* __restrict__ scalef){
  long i=(long)blockIdx.x*256+threadIdx.x;
  if(i >= (long)9232*3072/8) return;
  long e=i*8;
  int c=(int)(e%3072);
  int b=(int)((e/3072)/577);
  float sc=scalef[b*4 + c/768];
  u32x4 u = *(u32x4*)(hid+e);
  u16* pu=(u16*)&u;
#pragma unroll
  for(int j=0;j<8;j++) pu[j]=f2b(b2f(pu[j])*sc);
  *(u32x4*)(hid+e)=u;
}

__global__ void dgate_kernel(const u16* __restrict__ dn, const float* __restrict__ gw,
                             const float* __restrict__ gb, float* __restrict__ dgate){
  __shared__ float tmp[4];
  int b=blockIdx.x;
  const u16* row = dn + (size_t)b*577*3072;
  float a=0.f;
  for(int c=threadIdx.x;c<3072;c+=256) a+=b2f(row[c])*gw[c];
  a=block_sum(a,tmp);
  if(threadIdx.x==0) dgate[b]=1.f/(1.f+__expf(-(a+gb[0])));
}

// ---------------- generic batched GEMM: C = epilogue(alpha*gate * A*B^T) -----
// A: [M,K] bf16 row-major (lda), B: [N,K] bf16 row-major (ldb).
// 128x128 tile, 4 waves (2x2), each wave 64x64 = 4x4 x mfma 16x16x32 bf16.
constexpr int F_BIAS=1, F_RES=2, F_GELU=4, F_GATE=8, F_RESF32=16, F_OUTF32=32;

DEV int swz(int u){ int row=u>>2, sl=u&3; return row*4 + (sl ^ ((row>>1)&3)); }

template<int FLAGS>
__global__ __launch_bounds__(256,2) void gemm_bt(
  const u16* __restrict__ A, long lda, long szA,
  const u16* __restrict__ B, long ldb, long szB,
  void* __restrict__ Cv, long ldc, long szC,
  const float* __restrict__ bias,
  const void* __restrict__ resv, long ldr, long szR, float res_scale,
  const float* __restrict__ gate,
  float alpha, int M, int N, int K)
{
  __shared__ u16 shA[128*32];
  __shared__ u16 shB[128*32];
  const int z = blockIdx.z;
  A += (long)z*szA; B += (long)z*szB;
  const int tid=threadIdx.x, lane=tid&63, wid=tid>>6;
  const int wr=wid>>1, wc=wid&1;
  const long m0=(long)blockIdx.x*128, n0=(long)blockIdx.y*128;
  f32x4 acc[4][4];
#pragma unroll
  for(int i=0;i<4;i++)
#pragma unroll
    for(int j=0;j<4;j++){ f32x4 zv={0.f,0.f,0.f,0.f}; acc[i][j]=zv; }

  const int u0=tid, u1=256+tid;
  const int r0_=u0>>2, kc0=(u0&3)*8;
  const int r1_=u1>>2, kc1=(u1&3)*8;
  for(int k0=0;k0<K;k0+=32){
    long ar0 = m0 + r0_; if(ar0>=M) ar0=M-1;
    long ar1 = m0 + r1_; if(ar1>=M) ar1=M-1;
    long br0 = n0 + r0_; if(br0>=N) br0=N-1;
    long br1 = n0 + r1_; if(br1>=N) br1=N-1;
    u32x4 ra0 = *(const u32x4*)(A + ar0*lda + k0 + kc0);
    u32x4 ra1 = *(const u32x4*)(A + ar1*lda + k0 + kc1);
    u32x4 rb0 = *(const u32x4*)(B + br0*ldb + k0 + kc0);
    u32x4 rb1 = *(const u32x4*)(B + br1*ldb + k0 + kc1);
    __syncthreads();
    ((u32x4*)shA)[swz(u0)] = ra0;
    ((u32x4*)shA)[swz(u1)] = ra1;
    ((u32x4*)shB)[swz(u0)] = rb0;
    ((u32x4*)shB)[swz(u1)] = rb1;
    __syncthreads();
    const int ks = lane>>4, rr = lane&15;
    u32x4 av[4], bv[4];
#pragma unroll
    for(int mi=0;mi<4;mi++) av[mi] = ((const u32x4*)shA)[swz((wr*64+mi*16+rr)*4+ks)];
#pragma unroll
    for(int ni=0;ni<4;ni++) bv[ni] = ((const u32x4*)shB)[swz((wc*64+ni*16+rr)*4+ks)];
#pragma unroll
    for(int mi=0;mi<4;mi++)
#pragma unroll
      for(int ni=0;ni<4;ni++)
        asm volatile("v_mfma_f32_16x16x32_bf16 %0, %1, %2, %0"
                     : "+v"(acc[mi][ni]) : "v"(av[mi]), "v"(bv[ni]));
  }
  const float* resf = (const float*)resv + (long)z*szR;
  const u16*   resh = (const u16*)resv   + (long)z*szR;
  float* Cf = (float*)Cv + (long)z*szC;
  u16*   Ch = (u16*)Cv   + (long)z*szC;
  float gv = (FLAGS&F_GATE)? gate[z] : 1.f;
#pragma unroll
  for(int mi=0;mi<4;mi++){
#pragma unroll
    for(int ni=0;ni<4;ni++){
      long c0 = n0 + wc*64 + ni*16 + (lane&15);
      if(c0>=N) continue;
      float bb = (FLAGS&F_BIAS)? bias[c0] : 0.f;
#pragma unroll
      for(int r=0;r<4;r++){
        long rw = m0 + wr*64 + mi*16 + (lane>>4)*4 + r;
        if(rw>=M) continue;
        float t = acc[mi][ni][r]*alpha*gv + bb;
        if(FLAGS&F_RES){
          float rvv = (FLAGS&F_RESF32)? resf[rw*ldr+c0] : b2f(resh[rw*ldr+c0]);
          t += res_scale*rvv;
        }
        if(FLAGS&F_GELU) t = 0.5f*t*(1.f+erff(t*0.70710678118654752f));
        if(FLAGS&F_OUTF32) Cf[rw*ldc+c0]=t;
        else               Ch[rw*ldc+c0]=f2b(t);
      }
    }
  }
}

static inline dim3 ggrid(int M,int N,int nb){ return dim3((M+127)/128,(N+127)/128,nb); }

extern "C" void kernel_launch(void* const* d_in, const int* in_sizes, int n_in,
                              void* d_out, int out_size, void* d_ws, size_t ws_size,
                              hipStream_t stream){
  const int BNr=16*577;            // 9232 rows
  const float* x      = (const float*)d_in[0];
  const float* ln1_g  = (const float*)d_in[1];
  const float* ln1_b  = (const float*)d_in[2];
  const float* ad_ln_g= (const float*)d_in[3];
  const float* ad_ln_b= (const float*)d_in[4];
  const float* ad_w   = (const float*)d_in[5];
  const float* w_qkv  = (const float*)d_in[6];
  const float* w_proj = (const float*)d_in[7];
  const float* b_proj = (const float*)d_in[8];
  const float* ln2_g  = (const float*)d_in[9];
  const float* ln2_b  = (const float*)d_in[10];
  const float* fc1_w  = (const float*)d_in[11];
  const float* fc1_b  = (const float*)d_in[12];
  const float* fc2_w  = (const float*)d_in[13];
  const float* fc2_b  = (const float*)d_in[14];
  const float* r_ln_g = (const float*)d_in[15];
  const float* r_ln_b = (const float*)d_in[16];
  const float* r_proj_w=(const float*)d_in[17];
  const float* r_proj_b=(const float*)d_in[18];
  const float* r_gate_w=(const float*)d_in[19];
  const float* r_gate_b=(const float*)d_in[20];
  const float* r_scale =(const float*)d_in[21];
  const float* d_ln_g = (const float*)d_in[22];
  const float* d_ln_b = (const float*)d_in[23];
  const float* d_outw = (const float*)d_in[24];
  const float* d_gate_w=(const float*)d_in[25];
  const float* d_gate_b=(const float*)d_in[26];

  char* ws=(char*)d_ws;
  size_t off=0;
  auto take=[&](size_t nb){ size_t r=off; off=(off+nb+255)&~(size_t)255; return r; };
  auto al  =[&](size_t v){ return (v+255)&~(size_t)255; };
  // persistent
  const size_t o_qkvT = take((size_t)2304*768*2);
  const size_t o_adT  = take((size_t)768*768*2);
  const size_t o_projT= take((size_t)768*768*2);
  const size_t o_fc1T = take((size_t)3072*768*2);
  const size_t o_fc2T = take((size_t)768*3072*2);
  const size_t o_doutT= take((size_t)3072*3072*2);
  const size_t o_x2   = take((size_t)BNr*768*4);       // f32
  const size_t o_hid  = take((size_t)BNr*3072*2);
  const size_t o_stats= take((size_t)BNr*2*4);
  const size_t o_rn   = take((size_t)BNr*4);
  const size_t o_sum  = take((size_t)16*6144*4);
  const size_t o_scalef=take(64*4);
  const size_t o_dg   = take(64);
  // phase-A scratch chain
  const size_t o_h    = take((size_t)BNr*768*2);
  const size_t o_lnh  = take((size_t)BNr*768*2);
  const size_t o_metric=take((size_t)BNr*768*2);
  const size_t o_qk   = take((size_t)BNr*1536*2);
  const size_t o_v    = take((size_t)BNr*768*2);
  const size_t o_qh   = take((size_t)192*577*64*2);
  const size_t o_kh   = take((size_t)192*577*64*2);
  const size_t o_vT   = take((size_t)192*64*608*2);
  (void)o_v; (void)o_vT; (void)ws_size; (void)in_sizes; (void)n_in; (void)out_size;
  // phase-A aliases (lifetimes verified: dead-before-write)
  const size_t o_S    = o_qk;       // 32-bh score chunk (22.5MB <= qk 28.4MB)
  const size_t o_aoh  = o_metric;
  const size_t o_aout = o_h;
  const size_t o_h2   = o_lnh;
  // phase-B aliases over the (dead) phase-A scratch
  const size_t o_dn   = o_h;
  const size_t o_aff  = al(o_dn + (size_t)BNr*3072*2);
  const size_t o_dnTb = al(o_aff + (size_t)16*577*608*2);
  const size_t o_diff = al(o_dnTb + (size_t)4*3072*608*2);
  const size_t o_hact = o_dn;

  u16* qkvT=(u16*)(ws+o_qkvT); u16* adT=(u16*)(ws+o_adT); u16* projT=(u16*)(ws+o_projT);
  u16* fc1T=(u16*)(ws+o_fc1T); u16* fc2T=(u16*)(ws+o_fc2T); u16* doutT=(u16*)(ws+o_doutT);
  float* x2=(float*)(ws+o_x2); u16* hid=(u16*)(ws+o_hid);
  float* stats=(float*)(ws+o_stats); float* rn=(float*)(ws+o_rn);
  float* summ=(float*)(ws+o_sum); float* scalef=(float*)(ws+o_scalef); float* dgate=(float*)(ws+o_dg);
  u16* hbuf=(u16*)(ws+o_h); u16* lnh=(u16*)(ws+o_lnh); u16* metric=(u16*)(ws+o_metric);
  u16* qkbuf=(u16*)(ws+o_qk); u16* vbuf=(u16*)(ws+o_v);
  u16* qh=(u16*)(ws+o_qh); u16* kh=(u16*)(ws+o_kh); u16* vT=(u16*)(ws+o_vT);
  u16* Sc=(u16*)(ws+o_S); u16* aoh=(u16*)(ws+o_aoh); u16* aout=(u16*)(ws+o_aout);
  u16* h2=(u16*)(ws+o_h2);
  u16* dn=(u16*)(ws+o_dn); u16* aff=(u16*)(ws+o_aff); u16* dnTb=(u16*)(ws+o_dnTb);
  u16* diff=(u16*)(ws+o_diff); u16* hact=(u16*)(ws+o_hact);

  dim3 blk(256);
  // ---- weight transposes f32 -> bf16 [N,K]
  transpose_pad<float><<<dim3(72,24,1),blk,0,stream>>>(w_qkv, qkvT, 768,2304,768, 0,0);
  transpose_pad<float><<<dim3(24,24,1),blk,0,stream>>>(ad_w,  adT,  768,768, 768, 0,0);
  transpose_pad<float><<<dim3(24,24,1),blk,0,stream>>>(w_proj,projT,768,768, 768, 0,0);
  transpose_pad<float><<<dim3(96,24,1),blk,0,stream>>>(fc1_w, fc1T, 768,3072,768, 0,0);
  transpose_pad<float><<<dim3(24,96,1),blk,0,stream>>>(fc2_w, fc2T, 3072,768,3072,0,0);
  transpose_pad<float><<<dim3(96,96,1),blk,0,stream>>>(d_outw,doutT,3072,3072,3072,0,0);
  // ---- attention block
  ln_rows<float><<<BNr,blk,0,stream>>>(x, ln1_g, ln1_b, hbuf, 768);
  ln_rows<u16>  <<<BNr,blk,0,stream>>>(hbuf, ad_ln_g, ad_ln_b, lnh, 768);
  gemm_bt<F_RES><<<ggrid(BNr,768,1),blk,0,stream>>>(lnh,768,0, adT,768,0, metric,768,0,
      nullptr, hbuf,768,0, 1.f, nullptr, 1.f, BNr,768,768);
  gemm_bt<0><<<ggrid(BNr,1536,1),blk,0,stream>>>(metric,768,0, qkvT,768,0, qkbuf,1536,0,
      nullptr, nullptr,0,0,0.f, nullptr, 1.f, BNr,1536,768);
  gemm_bt<0><<<ggrid(BNr,768,1),blk,0,stream>>>(hbuf,768,0, qkvT+(size_t)1536*768,768,0, vbuf,768,0,
      nullptr, nullptr,0,0,0.f, nullptr, 1.f, BNr,768,768);
  split_heads<<<3462,blk,0,stream>>>(qkbuf, qh, kh);
  make_vT<<<29184,blk,0,stream>>>(vbuf, vT);
  for(int c=0;c<6;c++){
    const u16* qc=qh+(size_t)c*32*577*64;
    const u16* kc=kh+(size_t)c*32*577*64;
    gemm_bt<0><<<dim3(5,5,32),blk,0,stream>>>(qc,64,(long)577*64, kc,64,(long)577*64,
        Sc,608,(long)577*608, nullptr, nullptr,0,0,0.f, nullptr, 0.125f, 577,577,64);
    softmax_rows<<<32*577,blk,0,stream>>>(Sc,577,608, nullptr,577, 1.f);
    gemm_bt<0><<<dim3(5,1,32),blk,0,stream>>>(Sc,608,(long)577*608, vT+(size_t)c*32*64*608,608,(long)64*608,
        aoh+(size_t)c*32*577*64,64,(long)577*64, nullptr, nullptr,0,0,0.f, nullptr, 1.f, 577,64,608);
  }
  merge_heads<<<3462,blk,0,stream>>>(aoh, aout);
  gemm_bt<F_RES|F_BIAS|F_RESF32|F_OUTF32><<<ggrid(BNr,768,1),blk,0,stream>>>(aout,768,0, projT,768,0,
      x2,768,0, b_proj, x,768,0, 1.f, nullptr, 1.f, BNr,768,768);
  // ---- MLP front
  ln_rows<float><<<BNr,blk,0,stream>>>(x2, ln2_g, ln2_b, h2, 768);
  gemm_bt<F_BIAS><<<ggrid(BNr,3072,1),blk,0,stream>>>(h2,768,0, fc1T,768,0, hid,3072,0,
      fc1_b, nullptr,0,0,0.f, nullptr, 1.f, BNr,3072,768);
  // ---- router
  row_stats<<<BNr,blk,0,stream>>>(hid, stats, 3072);
  summary_kernel<<<dim3(12,16),blk,0,stream>>>(hid, stats, r_ln_g, r_ln_b, summ);
  router_kernel<<<16,blk,0,stream>>>(summ, r_proj_w, r_proj_b, r_gate_w, r_gate_b, r_scale, scalef);
  scale_hid<<<13848,blk,0,stream>>>(hid, scalef);
  // ---- token diffusion
  dn_kernel<<<BNr,blk,0,stream>>>(hid, d_ln_g, d_ln_b, dn, rn);
  dgate_kernel<<<16,blk,0,stream>>>(dn, d_gate_w, d_gate_b, dgate);
  gemm_bt<0><<<dim3(5,5,16),blk,0,stream>>>(dn,3072,(long)577*3072, dn,3072,(long)577*3072,
      aff,608,(long)577*608, nullptr, nullptr,0,0,0.f, nullptr, 1.f, 577,577,3072);
  softmax_rows<<<BNr,blk,0,stream>>>(aff,577,608, rn,577, 0.01804219634f);
  for(int g4=0; g4<4; ++g4){
    transpose_pad<u16><<<dim3(96,19,4),blk,0,stream>>>(dn+(size_t)g4*4*577*3072, dnTb,
        577,3072,608, (long)577*3072, (long)3072*608);
    gemm_bt<F_RES><<<dim3(5,24,4),blk,0,stream>>>(aff+(size_t)g4*4*577*608,608,(long)577*608,
        dnTb,608,(long)3072*608, diff+(size_t)g4*4*577*3072,3072,(long)577*3072,
        nullptr, dn+(size_t)g4*4*577*3072,3072,(long)577*3072, -1.f, nullptr, 1.f, 577,3072,608);
  }
  gemm_bt<F_RES|F_GATE|F_GELU><<<dim3(5,24,16),blk,0,stream>>>(diff,3072,(long)577*3072,
      doutT,3072,0, hact,3072,(long)577*3072, nullptr, hid,3072,(long)577*3072, 1.f,
      dgate, 1.f, 577,3072,3072);
  // ---- fc2 + final residual (f32 out)
  gemm_bt<F_RES|F_BIAS|F_RESF32|F_OUTF32><<<ggrid(BNr,768,1),blk,0,stream>>>(hact,3072,0,
      fc2T,3072,0, d_out,768,0, fc2_b, x2,768,0, 1.f, nullptr, 1.f, BNr,768,3072);
}

// Round 2
// 1553.373 us; speedup vs baseline: 1.0739x; 1.0739x over previous
//
#include <hip/hip_runtime.h>
#include <math.h>

typedef unsigned short u16;
typedef unsigned int   u32;
typedef __attribute__((ext_vector_type(4))) float f32x4;
typedef __attribute__((ext_vector_type(4))) u32   u32x4;

#define DEV __device__ __forceinline__
#define AS1 __attribute__((address_space(1)))
#define AS3 __attribute__((address_space(3)))

DEV float b2f(u16 u){ u32 x = ((u32)u)<<16; float f; __builtin_memcpy(&f,&x,4); return f; }
DEV u16 f2b(float f){ u32 x; __builtin_memcpy(&x,&f,4); u32 r = x + 0x7FFFu + ((x>>16)&1u); return (u16)(r>>16); }

DEV float ldf(const float* p, long i){ return p[i]; }
DEV float ldf(const u16*   p, long i){ return b2f(p[i]); }

DEV void gload16(const u16* g, u16* l){
  __builtin_amdgcn_global_load_lds((const AS1 u32*)(const void*)g,
                                   (AS3 u32*)(void*)l, 16, 0, 0);
}

DEV float wave_sum(float v){
#pragma unroll
  for(int o=32;o;o>>=1) v += __shfl_down(v,o,64);
  return v;
}
DEV float wave_max(float v){
#pragma unroll
  for(int o=32;o;o>>=1) v = fmaxf(v, __shfl_down(v,o,64));
  return v;
}
// blockDim.x == 256 assumed everywhere below.
DEV float block_sum(float v, float* tmp){
  v = wave_sum(v);
  if((threadIdx.x&63)==0) tmp[threadIdx.x>>6]=v;
  __syncthreads();
  float r = tmp[0]+tmp[1]+tmp[2]+tmp[3];
  __syncthreads();
  return r;
}
DEV float block_max(float v, float* tmp){
  v = wave_max(v);
  if((threadIdx.x&63)==0) tmp[threadIdx.x>>6]=v;
  __syncthreads();
  float r = fmaxf(fmaxf(tmp[0],tmp[1]),fmaxf(tmp[2],tmp[3]));
  __syncthreads();
  return r;
}

// ---------------- transpose (+K-pad with zeros), out always bf16 -------------
template<typename TI>
__global__ void transpose_pad(const TI* __restrict__ in, u16* __restrict__ out,
                              int R, int C, int Rpad, long strideI, long strideO){
  __shared__ u16 t[32][33];
  in  += (long)blockIdx.z*strideI;
  out += (long)blockIdx.z*strideO;
  int tx = threadIdx.x & 31, ty = threadIdx.x >> 5;
  int bc = blockIdx.x*32, br = blockIdx.y*32;
#pragma unroll
  for(int i=0;i<32;i+=8){
    int r = br+ty+i, c = bc+tx;
    float v = (r<R && c<C) ? ldf(in,(long)r*C+c) : 0.f;
    t[ty+i][tx] = f2b(v);
  }
  __syncthreads();
#pragma unroll
  for(int i=0;i<32;i+=8){
    int c = bc+ty+i, r = br+tx;
    if(c<C && r<Rpad) out[(long)c*Rpad + r] = t[tx][ty+i];
  }
}

// ---------------- LayerNorm rows ---------------------------------------------
template<typename TI>
__global__ void ln_rows(const TI* __restrict__ x, const float* __restrict__ g,
                        const float* __restrict__ b, u16* __restrict__ y, int W){
  __shared__ float tmp[4];
  long base=(long)blockIdx.x*W;
  float s=0.f, ss=0.f;
  for(int c=threadIdx.x;c<W;c+=256){ float v=ldf(x,base+c); s+=v; ss+=v*v; }
  s=block_sum(s,tmp); ss=block_sum(ss,tmp);
  float mu=s/W;
  float rstd=rsqrtf(fmaxf(ss/W-mu*mu,0.f)+1e-5f);
  for(int c=threadIdx.x;c<W;c+=256){
    float v=ldf(x,base+c);
    y[base+c]=f2b((v-mu)*rstd*g[c]+b[c]);
  }
}

__global__ void row_stats(const u16* __restrict__ x, float* __restrict__ stats, int W){
  __shared__ float tmp[4];
  long base=(long)blockIdx.x*W;
  float s=0.f,ss=0.f;
  for(int c=threadIdx.x;c<W;c+=256){ float v=b2f(x[base+c]); s+=v; ss+=v*v; }
  s=block_sum(s,tmp); ss=block_sum(ss,tmp);
  if(threadIdx.x==0){
    float mu=s/W;
    stats[2*(long)blockIdx.x]=mu;
    stats[2*(long)blockIdx.x+1]=rsqrtf(fmaxf(ss/W-mu*mu,0.f)+1e-5f);
  }
}

// dn = LN(hid; d_ln), rn = 1/max(||dn||,1e-12)
__global__ void dn_kernel(const u16* __restrict__ x, const float* __restrict__ g,
                          const float* __restrict__ b, u16* __restrict__ dn,
                          float* __restrict__ rn){
  const int W=3072;
  __shared__ float tmp[4];
  long base=(long)blockIdx.x*(long)W;
  float s=0.f,ss=0.f;
  for(int c=threadIdx.x;c<W;c+=256){ float v=b2f(x[base+c]); s+=v; ss+=v*v; }
  s=block_sum(s,tmp); ss=block_sum(ss,tmp);
  float mu=s/W;
  float rstd=rsqrtf(fmaxf(ss/W-mu*mu,0.f)+1e-5f);
  float sq=0.f;
  for(int c=threadIdx.x;c<W;c+=256){
    float v=(b2f(x[base+c])-mu)*rstd*g[c]+b[c];
    sq+=v*v;
  }
  sq=block_sum(sq,tmp);
  float r=1.f/fmaxf(sqrtf(sq),1e-12f);
  for(int c=threadIdx.x;c<W;c+=256){
    float v=(b2f(x[base+c])-mu)*rstd*g[c]+b[c];
    dn[base+c]=f2b(v);
  }
  if(threadIdx.x==0) rn[blockIdx.x]=r;
}

// ------------- softmax over rows (in-place bf16), optional row/col scaling ---
__global__ void softmax_rows(u16* __restrict__ S, int W, int Wp,
                             const float* __restrict__ rs, int rpb, float alpha){
  __shared__ float tmp[4];
  long row = blockIdx.x;
  u16* p = S + row*(long)Wp;
  float rowscale = alpha;
  const float* rsb = nullptr;
  if(rs){ long bt=row/rpb; int m=(int)(row%rpb); rsb = rs + bt*(long)rpb; rowscale *= rsb[m]; }
  float mx=-3e38f;
  for(int c=threadIdx.x;c<W;c+=256){
    float v=b2f(p[c])*rowscale; if(rs) v*=rsb[c];
    mx=fmaxf(mx,v);
  }
  mx=block_max(mx,tmp);
  float sm=0.f;
  for(int c=threadIdx.x;c<W;c+=256){
    float v=b2f(p[c])*rowscale; if(rs) v*=rsb[c];
    sm+=__expf(v-mx);
  }
  sm=block_sum(sm,tmp);
  float inv=1.f/sm;
  for(int c=threadIdx.x;c<W;c+=256){
    float v=b2f(p[c])*rowscale; if(rs) v*=rsb[c];
    p[c]=f2b(__expf(v-mx)*inv);
  }
  for(int c=W+threadIdx.x;c<Wp;c+=256) p[c]=0;
}

// ---------------- attention head reshapes ------------------------------------
__global__ void split_heads(const u16* __restrict__ qk, u16* __restrict__ qh, u16* __restrict__ kh){
  int i = blockIdx.x*256+threadIdx.x;
  if(i >= 16*577*12*8) return;
  int dv = i&7; int h=(i>>3)%12; int bn=i/96;
  int b=bn/577, n=bn%577;
  long src=(long)bn*1536 + h*64 + dv*8;
  long dst=((long)((b*12+h)*577+n))*64 + dv*8;
  *(u32x4*)(qh+dst) = *(const u32x4*)(qk+src);
  *(u32x4*)(kh+dst) = *(const u32x4*)(qk+src+768);
}
__global__ void merge_heads(const u16* __restrict__ aoh, u16* __restrict__ aout){
  int i = blockIdx.x*256+threadIdx.x;
  if(i >= 16*577*12*8) return;
  int dv=i&7; int h=(i>>3)%12; int bn=i/96;
  int b=bn/577, n=bn%577;
  long dst=(long)bn*768 + h*64 + dv*8;
  long src=((long)((b*12+h)*577+n))*64 + dv*8;
  *(u32x4*)(aout+dst) = *(const u32x4*)(aoh+src);
}
__global__ void make_vT(const u16* __restrict__ v, u16* __restrict__ vT){
  long i = (long)blockIdx.x*256+threadIdx.x;
  if(i >= (long)192*64*608) return;
  int n=(int)(i%608); long q=i/608; int d=(int)(q&63); int bh=(int)(q>>6);
  int b=bh/12, h=bh%12;
  u16 val=0;
  if(n<577) val = v[((long)(b*577+n))*768 + h*64 + d];
  vT[i]=val;
}

// ---------------- router -----------------------------------------------------
__global__ void summary_kernel(const u16* __restrict__ hid, const float* __restrict__ stats,
                               const float* __restrict__ rg, const float* __restrict__ rb,
                               float* __restrict__ summ){
  int b=blockIdx.y;
  int c=blockIdx.x*256+threadIdx.x;   // grid.x=12 -> c<3072
  const u16* hb=hid+(size_t)b*577*3072;
  const float* st=stats+(size_t)b*577*2;
  float g=rg[c], be=rb[c];
  float cls=(b2f(hb[c])-st[0])*st[1]*g+be;
  float acc=0.f;
  for(int n=1;n<577;n++) acc += (b2f(hb[(size_t)n*3072+c])-st[2*n])*st[2*n+1];
  summ[(size_t)b*6144+c]        = 1.0f*cls;                         // CLS_MIX
  summ[(size_t)b*6144+3072+c]   = 0.5f*(g*(acc*(1.f/576.f))+be);    // MEAN_MIX
}

__global__ void router_kernel(const float* __restrict__ summ, const float* __restrict__ pw,
                              const float* __restrict__ pb, const float* __restrict__ gw,
                              const float* __restrict__ gb, const float* __restrict__ rsc,
                              float* __restrict__ scalef){
  __shared__ float tmp[4];
  int b=blockIdx.x;
  float a0=0,a1=0,a2=0,a3=0,a4=0;
  for(int c=threadIdx.x;c<6144;c+=256){
    float sv=summ[(size_t)b*6144+c];
    a0+=sv*pw[c*4+0]; a1+=sv*pw[c*4+1]; a2+=sv*pw[c*4+2]; a3+=sv*pw[c*4+3];
    a4+=sv*gw[c];
  }
  a0=block_sum(a0,tmp); a1=block_sum(a1,tmp); a2=block_sum(a2,tmp);
  a3=block_sum(a3,tmp); a4=block_sum(a4,tmp);
  if(threadIdx.x==0){
    float l0=a0+pb[0], l1=a1+pb[1], l2=a2+pb[2], l3=a3+pb[3];
    float mx=fmaxf(fmaxf(l0,l1),fmaxf(l2,l3));
    float e0=__expf(l0-mx),e1=__expf(l1-mx),e2=__expf(l2-mx),e3=__expf(l3-mx);
    float s=e0+e1+e2+e3;
    float gate=1.f/(1.f+__expf(-(a4+gb[0])));
    float w0=e0/s,w1=e1/s,w2=e2/s,w3=e3/s;
    scalef[b*4+0]=1.f+gate*rsc[0]*(4.f*w0-1.f);
    scalef[b*4+1]=1.f+gate*rsc[1]*(4.f*w1-1.f);
    scalef[b*4+2]=1.f+gate*rsc[2]*(4.f*w2-1.f);
    scalef[b*4+3]=1.f+gate*rsc[3]*(4.f*w3-1.f);
  }
}

__global__ void scale_hid(u16* __restrict__ hid, const float* __restrict__ scalef){
  long i=(long)blockIdx.x*256+threadIdx.x;
  if(i >= (long)9232*3072/8) return;
  long e=i*8;
  int c=(int)(e%3072);
  int b=(int)((e/3072)/577);
  float sc=scalef[b*4 + c/768];
  u32x4 u = *(u32x4*)(hid+e);
  u16* pu=(u16*)&u;
#pragma unroll
  for(int j=0;j<8;j++) pu[j]=f2b(b2f(pu[j])*sc);
  *(u32x4*)(hid+e)=u;
}

__global__ void dgate_kernel(const u16* __restrict__ dn, const float* __restrict__ gw,
                             const float* __restrict__ gb, float* __restrict__ dgate){
  __shared__ float tmp[4];
  int b=blockIdx.x;
  const u16* row = dn + (size_t)b*577*3072;
  float a=0.f;
  for(int c=threadIdx.x;c<3072;c+=256) a+=b2f(row[c])*gw[c];
  a=block_sum(a,tmp);
  if(threadIdx.x==0) dgate[b]=1.f/(1.f+__expf(-(a+gb[0])));
}

// ---------------- generic batched GEMM: C = epilogue(alpha*gate * A*B^T) -----
// A: [M,K] bf16 row-major (lda), B: [N,K] bf16 row-major (ldb).
// 128x128 tile, 4 waves (2x2), each wave 64x64 = 4x4 x mfma 16x16x32 bf16.
// Staging: global_load_lds width=16, linear LDS dest, PRE-SWIZZLED global src
// (m173 pattern) so ds_read side keeps the conflict-free XOR slot swizzle.
// Grid: 1D, bijective XCD chunk swizzle (m204), decomposed x-fastest.
constexpr int F_BIAS=1, F_RES=2, F_GELU=4, F_GATE=8, F_RESF32=16, F_OUTF32=32;

DEV int swz(int u){ int row=u>>2, sl=u&3; return row*4 + (sl ^ ((row>>1)&3)); }

template<int FLAGS>
__global__ __launch_bounds__(256,2) void gemm_bt(
  const u16* __restrict__ A, long lda, long szA,
  const u16* __restrict__ B, long ldb, long szB,
  void* __restrict__ Cv, long ldc, long szC,
  const float* __restrict__ bias,
  const void* __restrict__ resv, long ldr, long szR, float res_scale,
  const float* __restrict__ gate,
  float alpha, int M, int N, int K, int NX, int NY)
{
  __shared__ alignas(16) u16 shA[128*32];
  __shared__ alignas(16) u16 shB[128*32];
  // bijective XCD chunk swizzle (m204): round-robin orig -> contiguous chunks
  const int nwg = (int)gridDim.x;
  const int orig = (int)blockIdx.x;
  const int q = nwg>>3, r = nwg&7;
  const int xcd = orig&7, idx = orig>>3;
  const int wg = (xcd<r ? xcd*(q+1) : r*(q+1)+(xcd-r)*q) + idx;
  const int bx = wg % NX; const int t_ = wg / NX;
  const int by = t_ % NY; const int z  = t_ / NY;

  A += (long)z*szA; B += (long)z*szB;
  const int tid=threadIdx.x, lane=tid&63, wid=tid>>6;
  const int wr=wid>>1, wc=wid&1;
  const long m0=(long)bx*128, n0=(long)by*128;
  f32x4 acc[4][4];
#pragma unroll
  for(int i=0;i<4;i++)
#pragma unroll
    for(int j=0;j<4;j++){ f32x4 zv={0.f,0.f,0.f,0.f}; acc[i][j]=zv; }

  // staging addresses (k-invariant): wave wid stages rows [wid*32, wid*32+32)
  // chunk i: 16 rows; lane -> row lr=l>>2, slot lsl=l&3; global k-col is
  // slot XOR-swizzled by tile row so LDS stays linear for global_load_lds.
  const int lr = lane>>2, lsl = lane&3;
  const u16* pA[2]; const u16* pB[2]; u16* lA[2]; u16* lB[2];
#pragma unroll
  for(int i=0;i<2;i++){
    int ra = wid*32 + i*16 + lr;                 // tile row (logical LDS row)
    int kc = (lsl ^ ((ra>>1)&3))*8;              // pre-swizzled k-col (elems)
    long gr = m0+ra; if(gr>=M) gr=M-1;
    long gb = n0+ra; if(gb>=N) gb=N-1;
    pA[i] = A + gr*lda + kc;
    pB[i] = B + gb*ldb + kc;
    lA[i] = shA + (wid*32 + i*16)*32;            // uniform per wave
    lB[i] = shB + (wid*32 + i*16)*32;
  }

  for(int k0=0;k0<K;k0+=32){
    __syncthreads();                              // prev tile fully consumed
#pragma unroll
    for(int i=0;i<2;i++){
      gload16(pA[i]+k0, lA[i]);
      gload16(pB[i]+k0, lB[i]);
    }
    __syncthreads();                              // vmcnt drain + visibility
    const int ks = lane>>4, rr = lane&15;
    u32x4 av[4], bv[4];
#pragma unroll
    for(int mi=0;mi<4;mi++) av[mi] = ((const u32x4*)shA)[swz((wr*64+mi*16+rr)*4+ks)];
#pragma unroll
    for(int ni=0;ni<4;ni++) bv[ni] = ((const u32x4*)shB)[swz((wc*64+ni*16+rr)*4+ks)];
#pragma unroll
    for(int mi=0;mi<4;mi++)
#pragma unroll
      for(int ni=0;ni<4;ni++)
        asm volatile("v_mfma_f32_16x16x32_bf16 %0, %1, %2, %0"
                     : "+v"(acc[mi][ni]) : "v"(av[mi]), "v"(bv[ni]));
  }
  const float* resf = (const float*)resv + (long)z*szR;
  const u16*   resh = (const u16*)resv   + (long)z*szR;
  float* Cf = (float*)Cv + (long)z*szC;
  u16*   Ch = (u16*)Cv   + (long)z*szC;
  float gv = (FLAGS&F_GATE)? gate[z] : 1.f;
#pragma unroll
  for(int mi=0;mi<4;mi++){
#pragma unroll
    for(int ni=0;ni<4;ni++){
      long c0 = n0 + wc*64 + ni*16 + (lane&15);
      if(c0>=N) continue;
      float bb = (FLAGS&F_BIAS)? bias[c0] : 0.f;
#pragma unroll
      for(int r2=0;r2<4;r2++){
        long rw = m0 + wr*64 + mi*16 + (lane>>4)*4 + r2;
        if(rw>=M) continue;
        float t = acc[mi][ni][r2]*alpha*gv + bb;
        if(FLAGS&F_RES){
          float rvv = (FLAGS&F_RESF32)? resf[rw*ldr+c0] : b2f(resh[rw*ldr+c0]);
          t += res_scale*rvv;
        }
        if(FLAGS&F_GELU) t = 0.5f*t*(1.f+erff(t*0.70710678118654752f));
        if(FLAGS&F_OUTF32) Cf[rw*ldc+c0]=t;
        else               Ch[rw*ldc+c0]=f2b(t);
      }
    }
  }
}

static inline int gpack(int M,int N,int nb,int& NX,int& NY){
  NX=(M+127)/128; NY=(N+127)/128; return NX*NY*nb;
}

extern "C" void kernel_launch(void* const* d_in, const int* in_sizes, int n_in,
                              void* d_out, int out_size, void* d_ws, size_t ws_size,
                              hipStream_t stream){
  const int BNr=16*577;            // 9232 rows
  const float* x      = (const float*)d_in[0];
  const float* ln1_g  = (const float*)d_in[1];
  const float* ln1_b  = (const float*)d_in[2];
  const float* ad_ln_g= (const float*)d_in[3];
  const float* ad_ln_b= (const float*)d_in[4];
  const float* ad_w   = (const float*)d_in[5];
  const float* w_qkv  = (const float*)d_in[6];
  const float* w_proj = (const float*)d_in[7];
  const float* b_proj = (const float*)d_in[8];
  const float* ln2_g  = (const float*)d_in[9];
  const float* ln2_b  = (const float*)d_in[10];
  const float* fc1_w  = (const float*)d_in[11];
  const float* fc1_b  = (const float*)d_in[12];
  const float* fc2_w  = (const float*)d_in[13];
  const float* fc2_b  = (const float*)d_in[14];
  const float* r_ln_g = (const float*)d_in[15];
  const float* r_ln_b = (const float*)d_in[16];
  const float* r_proj_w=(const float*)d_in[17];
  const float* r_proj_b=(const float*)d_in[18];
  const float* r_gate_w=(const float*)d_in[19];
  const float* r_gate_b=(const float*)d_in[20];
  const float* r_scale =(const float*)d_in[21];
  const float* d_ln_g = (const float*)d_in[22];
  const float* d_ln_b = (const float*)d_in[23];
  const float* d_outw = (const float*)d_in[24];
  const float* d_gate_w=(const float*)d_in[25];
  const float* d_gate_b=(const float*)d_in[26];

  char* ws=(char*)d_ws;
  size_t off=0;
  auto take=[&](size_t nb){ size_t r=off; off=(off+nb+255)&~(size_t)255; return r; };
  auto al  =[&](size_t v){ return (v+255)&~(size_t)255; };
  // persistent
  const size_t o_qkvT = take((size_t)2304*768*2);
  const size_t o_adT  = take((size_t)768*768*2);
  const size_t o_projT= take((size_t)768*768*2);
  const size_t o_fc1T = take((size_t)3072*768*2);
  const size_t o_fc2T = take((size_t)768*3072*2);
  const size_t o_doutT= take((size_t)3072*3072*2);
  const size_t o_x2   = take((size_t)BNr*768*4);       // f32
  const size_t o_hid  = take((size_t)BNr*3072*2);
  const size_t o_stats= take((size_t)BNr*2*4);
  const size_t o_rn   = take((size_t)BNr*4);
  const size_t o_sum  = take((size_t)16*6144*4);
  const size_t o_scalef=take(64*4);
  const size_t o_dg   = take(64);
  // phase-A scratch chain
  const size_t o_h    = take((size_t)BNr*768*2);
  const size_t o_lnh  = take((size_t)BNr*768*2);
  const size_t o_metric=take((size_t)BNr*768*2);
  const size_t o_qk   = take((size_t)BNr*1536*2);
  const size_t o_v    = take((size_t)BNr*768*2);
  const size_t o_qh   = take((size_t)192*577*64*2);
  const size_t o_kh   = take((size_t)192*577*64*2);
  const size_t o_vT   = take((size_t)192*64*608*2);
  (void)o_v; (void)o_vT; (void)ws_size; (void)in_sizes; (void)n_in; (void)out_size;
  // phase-A aliases (lifetimes verified: dead-before-write)
  const size_t o_S    = o_qk;       // 32-bh score chunk (22.5MB <= qk 28.4MB)
  const size_t o_aoh  = o_metric;
  const size_t o_aout = o_h;
  const size_t o_h2   = o_lnh;
  // phase-B aliases over the (dead) phase-A scratch
  const size_t o_dn   = o_h;
  const size_t o_aff  = al(o_dn + (size_t)BNr*3072*2);
  const size_t o_dnTb = al(o_aff + (size_t)16*577*608*2);
  const size_t o_diff = al(o_dnTb + (size_t)4*3072*608*2);
  const size_t o_hact = o_dn;

  u16* qkvT=(u16*)(ws+o_qkvT); u16* adT=(u16*)(ws+o_adT); u16* projT=(u16*)(ws+o_projT);
  u16* fc1T=(u16*)(ws+o_fc1T); u16* fc2T=(u16*)(ws+o_fc2T); u16* doutT=(u16*)(ws+o_doutT);
  float* x2=(float*)(ws+o_x2); u16* hid=(u16*)(ws+o_hid);
  float* stats=(float*)(ws+o_stats); float* rn=(float*)(ws+o_rn);
  float* summ=(float*)(ws+o_sum); float* scalef=(float*)(ws+o_scalef); float* dgate=(float*)(ws+o_dg);
  u16* hbuf=(u16*)(ws+o_h); u16* lnh=(u16*)(ws+o_lnh); u16* metric=(u16*)(ws+o_metric);
  u16* qkbuf=(u16*)(ws+o_qk); u16* vbuf=(u16*)(ws+o_v);
  u16* qh=(u16*)(ws+o_qh); u16* kh=(u16*)(ws+o_kh); u16* vT=(u16*)(ws+o_vT);
  u16* Sc=(u16*)(ws+o_S); u16* aoh=(u16*)(ws+o_aoh); u16* aout=(u16*)(ws+o_aout);
  u16* h2=(u16*)(ws+o_h2);
  u16* dn=(u16*)(ws+o_dn); u16* aff=(u16*)(ws+o_aff); u16* dnTb=(u16*)(ws+o_dnTb);
  u16* diff=(u16*)(ws+o_diff); u16* hact=(u16*)(ws+o_hact);

  dim3 blk(256);
  int NX, NY, ng;
  // ---- weight transposes f32 -> bf16 [N,K]
  transpose_pad<float><<<dim3(72,24,1),blk,0,stream>>>(w_qkv, qkvT, 768,2304,768, 0,0);
  transpose_pad<float><<<dim3(24,24,1),blk,0,stream>>>(ad_w,  adT,  768,768, 768, 0,0);
  transpose_pad<float><<<dim3(24,24,1),blk,0,stream>>>(w_proj,projT,768,768, 768, 0,0);
  transpose_pad<float><<<dim3(96,24,1),blk,0,stream>>>(fc1_w, fc1T, 768,3072,768, 0,0);
  transpose_pad<float><<<dim3(24,96,1),blk,0,stream>>>(fc2_w, fc2T, 3072,768,3072,0,0);
  transpose_pad<float><<<dim3(96,96,1),blk,0,stream>>>(d_outw,doutT,3072,3072,3072,0,0);
  // ---- attention block
  ln_rows<float><<<BNr,blk,0,stream>>>(x, ln1_g, ln1_b, hbuf, 768);
  ln_rows<u16>  <<<BNr,blk,0,stream>>>(hbuf, ad_ln_g, ad_ln_b, lnh, 768);
  ng=gpack(BNr,768,1,NX,NY);
  gemm_bt<F_RES><<<ng,blk,0,stream>>>(lnh,768,0, adT,768,0, metric,768,0,
      nullptr, hbuf,768,0, 1.f, nullptr, 1.f, BNr,768,768, NX,NY);
  ng=gpack(BNr,1536,1,NX,NY);
  gemm_bt<0><<<ng,blk,0,stream>>>(metric,768,0, qkvT,768,0, qkbuf,1536,0,
      nullptr, nullptr,0,0,0.f, nullptr, 1.f, BNr,1536,768, NX,NY);
  ng=gpack(BNr,768,1,NX,NY);
  gemm_bt<0><<<ng,blk,0,stream>>>(hbuf,768,0, qkvT+(size_t)1536*768,768,0, vbuf,768,0,
      nullptr, nullptr,0,0,0.f, nullptr, 1.f, BNr,768,768, NX,NY);
  split_heads<<<3462,blk,0,stream>>>(qkbuf, qh, kh);
  make_vT<<<29184,blk,0,stream>>>(vbuf, vT);
  for(int c=0;c<6;c++){
    const u16* qc=qh+(size_t)c*32*577*64;
    const u16* kc=kh+(size_t)c*32*577*64;
    ng=gpack(577,577,32,NX,NY);
    gemm_bt<0><<<ng,blk,0,stream>>>(qc,64,(long)577*64, kc,64,(long)577*64,
        Sc,608,(long)577*608, nullptr, nullptr,0,0,0.f, nullptr, 0.125f, 577,577,64, NX,NY);
    softmax_rows<<<32*577,blk,0,stream>>>(Sc,577,608, nullptr,577, 1.f);
    ng=gpack(577,64,32,NX,NY);
    gemm_bt<0><<<ng,blk,0,stream>>>(Sc,608,(long)577*608, vT+(size_t)c*32*64*608,608,(long)64*608,
        aoh+(size_t)c*32*577*64,64,(long)577*64, nullptr, nullptr,0,0,0.f, nullptr, 1.f, 577,64,608, NX,NY);
  }
  merge_heads<<<3462,blk,0,stream>>>(aoh, aout);
  ng=gpack(BNr,768,1,NX,NY);
  gemm_bt<F_RES|F_BIAS|F_RESF32|F_OUTF32><<<ng,blk,0,stream>>>(aout,768,0, projT,768,0,
      x2,768,0, b_proj, x,768,0, 1.f, nullptr, 1.f, BNr,768,768, NX,NY);
  // ---- MLP front
  ln_rows<float><<<BNr,blk,0,stream>>>(x2, ln2_g, ln2_b, h2, 768);
  ng=gpack(BNr,3072,1,NX,NY);
  gemm_bt<F_BIAS><<<ng,blk,0,stream>>>(h2,768,0, fc1T,768,0, hid,3072,0,
      fc1_b, nullptr,0,0,0.f, nullptr, 1.f, BNr,3072,768, NX,NY);
  // ---- router
  row_stats<<<BNr,blk,0,stream>>>(hid, stats, 3072);
  summary_kernel<<<dim3(12,16),blk,0,stream>>>(hid, stats, r_ln_g, r_ln_b, summ);
  router_kernel<<<16,blk,0,stream>>>(summ, r_proj_w, r_proj_b, r_gate_w, r_gate_b, r_scale, scalef);
  scale_hid<<<13848,blk,0,stream>>>(hid, scalef);
  // ---- token diffusion
  dn_kernel<<<BNr,blk,0,stream>>>(hid, d_ln_g, d_ln_b, dn, rn);
  dgate_kernel<<<16,blk,0,stream>>>(dn, d_gate_w, d_gate_b, dgate);
  ng=gpack(577,577,16,NX,NY);
  gemm_bt<0><<<ng,blk,0,stream>>>(dn,3072,(long)577*3072, dn,3072,(long)577*3072,
      aff,608,(long)577*608, nullptr, nullptr,0,0,0.f, nullptr, 1.f, 577,577,3072, NX,NY);
  softmax_rows<<<BNr,blk,0,stream>>>(aff,577,608, rn,577, 0.01804219634f);
  for(int g4=0; g4<4; ++g4){
    transpose_pad<u16><<<dim3(96,19,4),blk,0,stream>>>(dn+(size_t)g4*4*577*3072, dnTb,
        577,3072,608, (long)577*3072, (long)3072*608);
    ng=gpack(577,3072,4,NX,NY);
    gemm_bt<F_RES><<<ng,blk,0,stream>>>(aff+(size_t)g4*4*577*608,608,(long)577*608,
        dnTb,608,(long)3072*608, diff+(size_t)g4*4*577*3072,3072,(long)577*3072,
        nullptr, dn+(size_t)g4*4*577*3072,3072,(long)577*3072, -1.f, nullptr, 1.f, 577,3072,608, NX,NY);
  }
  ng=gpack(577,3072,16,NX,NY);
  gemm_bt<F_RES|F_GATE|F_GELU><<<ng,blk,0,stream>>>(diff,3072,(long)577*3072,
      doutT,3072,0, hact,3072,(long)577*3072, nullptr, hid,3072,(long)577*3072, 1.f,
      dgate, 1.f, 577,3072,3072, NX,NY);
  // ---- fc2 + final residual (f32 out)
  ng=gpack(BNr,768,1,NX,NY);
  gemm_bt<F_RES|F_BIAS|F_RESF32|F_OUTF32><<<ng,blk,0,stream>>>(hact,3072,0,
      fc2T,3072,0, d_out,768,0, fc2_b, x2,768,0, 1.f, nullptr, 1.f, BNr,768,3072, NX,NY);
}

// Round 3
// 1522.132 us; speedup vs baseline: 1.0960x; 1.0205x over previous
//
#include <hip/hip_runtime.h>
#include <math.h>

typedef unsigned short u16;
typedef unsigned int   u32;
typedef __attribute__((ext_vector_type(4))) float f32x4;
typedef __attribute__((ext_vector_type(4))) u32   u32x4;

#define DEV __device__ __forceinline__
#define AS1 __attribute__((address_space(1)))
#define AS3 __attribute__((address_space(3)))

DEV float b2f(u16 u){ u32 x = ((u32)u)<<16; float f; __builtin_memcpy(&f,&x,4); return f; }
DEV u16 f2b(float f){ u32 x; __builtin_memcpy(&x,&f,4); u32 r = x + 0x7FFFu + ((x>>16)&1u); return (u16)(r>>16); }

DEV float ldf(const float* p, long i){ return p[i]; }
DEV float ldf(const u16*   p, long i){ return b2f(p[i]); }

DEV void gload16(const u16* g, u16* l){
  __builtin_amdgcn_global_load_lds((const AS1 u32*)(const void*)g,
                                   (AS3 u32*)(void*)l, 16, 0, 0);
}

DEV float wave_sum(float v){
#pragma unroll
  for(int o=32;o;o>>=1) v += __shfl_down(v,o,64);
  return v;
}
DEV float wave_max(float v){
#pragma unroll
  for(int o=32;o;o>>=1) v = fmaxf(v, __shfl_down(v,o,64));
  return v;
}
// blockDim.x == 256 assumed in block_sum/block_max users.
DEV float block_sum(float v, float* tmp){
  v = wave_sum(v);
  if((threadIdx.x&63)==0) tmp[threadIdx.x>>6]=v;
  __syncthreads();
  float r = tmp[0]+tmp[1]+tmp[2]+tmp[3];
  __syncthreads();
  return r;
}
DEV float block_max(float v, float* tmp){
  v = wave_max(v);
  if((threadIdx.x&63)==0) tmp[threadIdx.x>>6]=v;
  __syncthreads();
  float r = fmaxf(fmaxf(tmp[0],tmp[1]),fmaxf(tmp[2],tmp[3]));
  __syncthreads();
  return r;
}

// ---------------- transpose (+K-pad with zeros), out always bf16 -------------
template<typename TI>
__global__ void transpose_pad(const TI* __restrict__ in, u16* __restrict__ out,
                              int R, int C, int Rpad, long strideI, long strideO){
  __shared__ u16 t[32][33];
  in  += (long)blockIdx.z*strideI;
  out += (long)blockIdx.z*strideO;
  int tx = threadIdx.x & 31, ty = threadIdx.x >> 5;
  int bc = blockIdx.x*32, br = blockIdx.y*32;
#pragma unroll
  for(int i=0;i<32;i+=8){
    int r = br+ty+i, c = bc+tx;
    float v = (r<R && c<C) ? ldf(in,(long)r*C+c) : 0.f;
    t[ty+i][tx] = f2b(v);
  }
  __syncthreads();
#pragma unroll
  for(int i=0;i<32;i+=8){
    int c = bc+ty+i, r = br+tx;
    if(c<C && r<Rpad) out[(long)c*Rpad + r] = t[tx][ty+i];
  }
}

// ---------------- LayerNorm rows ---------------------------------------------
template<typename TI>
__global__ void ln_rows(const TI* __restrict__ x, const float* __restrict__ g,
                        const float* __restrict__ b, u16* __restrict__ y, int W){
  __shared__ float tmp[4];
  long base=(long)blockIdx.x*W;
  float s=0.f, ss=0.f;
  for(int c=threadIdx.x;c<W;c+=256){ float v=ldf(x,base+c); s+=v; ss+=v*v; }
  s=block_sum(s,tmp); ss=block_sum(ss,tmp);
  float mu=s/W;
  float rstd=rsqrtf(fmaxf(ss/W-mu*mu,0.f)+1e-5f);
  for(int c=threadIdx.x;c<W;c+=256){
    float v=ldf(x,base+c);
    y[base+c]=f2b((v-mu)*rstd*g[c]+b[c]);
  }
}

__global__ void row_stats(const u16* __restrict__ x, float* __restrict__ stats, int W){
  __shared__ float tmp[4];
  long base=(long)blockIdx.x*W;
  float s=0.f,ss=0.f;
  for(int c=threadIdx.x;c<W;c+=256){ float v=b2f(x[base+c]); s+=v; ss+=v*v; }
  s=block_sum(s,tmp); ss=block_sum(ss,tmp);
  if(threadIdx.x==0){
    float mu=s/W;
    stats[2*(long)blockIdx.x]=mu;
    stats[2*(long)blockIdx.x+1]=rsqrtf(fmaxf(ss/W-mu*mu,0.f)+1e-5f);
  }
}

// dn = LN(hid*scale; d_ln), rn = 1/max(||dn||,1e-12)  (router scale fused in)
__global__ void dn_kernel(const u16* __restrict__ x, const float* __restrict__ g,
                          const float* __restrict__ b, const float* __restrict__ scalef,
                          u16* __restrict__ dn, float* __restrict__ rn){
  const int W=3072;
  __shared__ float tmp[4];
  __shared__ u16 rowb[3072];
  long row=(long)blockIdx.x;
  long base=row*(long)W;
  int bz=(int)(row/577);
  float s=0.f,ss=0.f;
  for(int c=threadIdx.x;c<W;c+=256){
    float sc=scalef[bz*4 + ((c>>8)/3)];
    float v=b2f(x[base+c])*sc;
    rowb[c]=f2b(v);
    s+=v; ss+=v*v;
  }
  s=block_sum(s,tmp); ss=block_sum(ss,tmp);
  float mu=s/W;
  float rstd=rsqrtf(fmaxf(ss/W-mu*mu,0.f)+1e-5f);
  float sq=0.f;
  for(int c=threadIdx.x;c<W;c+=256){
    float v=(b2f(rowb[c])-mu)*rstd*g[c]+b[c];
    sq+=v*v;
  }
  sq=block_sum(sq,tmp);
  float r=1.f/fmaxf(sqrtf(sq),1e-12f);
  for(int c=threadIdx.x;c<W;c+=256){
    float v=(b2f(rowb[c])-mu)*rstd*g[c]+b[c];
    dn[base+c]=f2b(v);
  }
  if(threadIdx.x==0) rn[blockIdx.x]=r;
}

// ------------- softmax over rows (in-place bf16), optional row/col scaling ---
__global__ void softmax_rows(u16* __restrict__ S, int W, int Wp,
                             const float* __restrict__ rs, int rpb, float alpha){
  __shared__ float tmp[4];
  long row = blockIdx.x;
  u16* p = S + row*(long)Wp;
  float rowscale = alpha;
  const float* rsb = nullptr;
  if(rs){ long bt=row/rpb; int m=(int)(row%rpb); rsb = rs + bt*(long)rpb; rowscale *= rsb[m]; }
  float mx=-3e38f;
  for(int c=threadIdx.x;c<W;c+=256){
    float v=b2f(p[c])*rowscale; if(rs) v*=rsb[c];
    mx=fmaxf(mx,v);
  }
  mx=block_max(mx,tmp);
  float sm=0.f;
  for(int c=threadIdx.x;c<W;c+=256){
    float v=b2f(p[c])*rowscale; if(rs) v*=rsb[c];
    sm+=__expf(v-mx);
  }
  sm=block_sum(sm,tmp);
  float inv=1.f/sm;
  for(int c=threadIdx.x;c<W;c+=256){
    float v=b2f(p[c])*rowscale; if(rs) v*=rsb[c];
    p[c]=f2b(__expf(v-mx)*inv);
  }
  for(int c=W+threadIdx.x;c<Wp;c+=256) p[c]=0;
}

// ---------------- attention head reshapes ------------------------------------
__global__ void split_heads(const u16* __restrict__ qk, u16* __restrict__ qh, u16* __restrict__ kh){
  int i = blockIdx.x*256+threadIdx.x;
  if(i >= 16*577*12*8) return;
  int dv = i&7; int h=(i>>3)%12; int bn=i/96;
  int b=bn/577, n=bn%577;
  long src=(long)bn*1536 + h*64 + dv*8;
  long dst=((long)((b*12+h)*577+n))*64 + dv*8;
  *(u32x4*)(qh+dst) = *(const u32x4*)(qk+src);
  *(u32x4*)(kh+dst) = *(const u32x4*)(qk+src+768);
}
__global__ void merge_heads(const u16* __restrict__ aoh, u16* __restrict__ aout){
  int i = blockIdx.x*256+threadIdx.x;
  if(i >= 16*577*12*8) return;
  int dv=i&7; int h=(i>>3)%12; int bn=i/96;
  int b=bn/577, n=bn%577;
  long dst=(long)bn*768 + h*64 + dv*8;
  long src=((long)((b*12+h)*577+n))*64 + dv*8;
  *(u32x4*)(aout+dst) = *(const u32x4*)(aoh+src);
}
__global__ void make_vT(const u16* __restrict__ v, u16* __restrict__ vT){
  long i = (long)blockIdx.x*256+threadIdx.x;
  if(i >= (long)192*64*608) return;
  int n=(int)(i%608); long q=i/608; int d=(int)(q&63); int bh=(int)(q>>6);
  int b=bh/12, h=bh%12;
  u16 val=0;
  if(n<577) val = v[((long)(b*577+n))*768 + h*64 + d];
  vT[i]=val;
}

// ---------------- router -----------------------------------------------------
__global__ void summary_kernel(const u16* __restrict__ hid, const float* __restrict__ stats,
                               const float* __restrict__ rg, const float* __restrict__ rb,
                               float* __restrict__ summ){
  int b=blockIdx.y;
  int c=blockIdx.x*256+threadIdx.x;   // grid.x=12 -> c<3072
  const u16* hb=hid+(size_t)b*577*3072;
  const float* st=stats+(size_t)b*577*2;
  float g=rg[c], be=rb[c];
  float cls=(b2f(hb[c])-st[0])*st[1]*g+be;
  float acc=0.f;
  for(int n=1;n<577;n++) acc += (b2f(hb[(size_t)n*3072+c])-st[2*n])*st[2*n+1];
  summ[(size_t)b*6144+c]        = 1.0f*cls;                         // CLS_MIX
  summ[(size_t)b*6144+3072+c]   = 0.5f*(g*(acc*(1.f/576.f))+be);    // MEAN_MIX
}

__global__ void router_kernel(const float* __restrict__ summ, const float* __restrict__ pw,
                              const float* __restrict__ pb, const float* __restrict__ gw,
                              const float* __restrict__ gb, const float* __restrict__ rsc,
                              float* __restrict__ scalef){
  __shared__ float tmp[4];
  int b=blockIdx.x;
  float a0=0,a1=0,a2=0,a3=0,a4=0;
  for(int c=threadIdx.x;c<6144;c+=256){
    float sv=summ[(size_t)b*6144+c];
    a0+=sv*pw[c*4+0]; a1+=sv*pw[c*4+1]; a2+=sv*pw[c*4+2]; a3+=sv*pw[c*4+3];
    a4+=sv*gw[c];
  }
  a0=block_sum(a0,tmp); a1=block_sum(a1,tmp); a2=block_sum(a2,tmp);
  a3=block_sum(a3,tmp); a4=block_sum(a4,tmp);
  if(threadIdx.x==0){
    float l0=a0+pb[0], l1=a1+pb[1], l2=a2+pb[2], l3=a3+pb[3];
    float mx=fmaxf(fmaxf(l0,l1),fmaxf(l2,l3));
    float e0=__expf(l0-mx),e1=__expf(l1-mx),e2=__expf(l2-mx),e3=__expf(l3-mx);
    float s=e0+e1+e2+e3;
    float gate=1.f/(1.f+__expf(-(a4+gb[0])));
    float w0=e0/s,w1=e1/s,w2=e2/s,w3=e3/s;
    scalef[b*4+0]=1.f+gate*rsc[0]*(4.f*w0-1.f);
    scalef[b*4+1]=1.f+gate*rsc[1]*(4.f*w1-1.f);
    scalef[b*4+2]=1.f+gate*rsc[2]*(4.f*w2-1.f);
    scalef[b*4+3]=1.f+gate*rsc[3]*(4.f*w3-1.f);
  }
}

__global__ void dgate_kernel(const u16* __restrict__ dn, const float* __restrict__ gw,
                             const float* __restrict__ gb, float* __restrict__ dgate){
  __shared__ float tmp[4];
  int b=blockIdx.x;
  const u16* row = dn + (size_t)b*577*3072;
  float a=0.f;
  for(int c=threadIdx.x;c<3072;c+=256) a+=b2f(row[c])*gw[c];
  a=block_sum(a,tmp);
  if(threadIdx.x==0) dgate[b]=1.f/(1.f+__expf(-(a+gb[0])));
}

constexpr int F_BIAS=1, F_RES=2, F_GELU=4, F_GATE=8, F_RESF32=16, F_OUTF32=32, F_SCRES=64;

// ---------------- 128x128 batched GEMM (kept for small/batched shapes) -------
DEV int swz(int u){ int row=u>>2, sl=u&3; return row*4 + (sl ^ ((row>>1)&3)); }

template<int FLAGS>
__global__ __launch_bounds__(256,2) void gemm_bt(
  const u16* __restrict__ A, long lda, long szA,
  const u16* __restrict__ B, long ldb, long szB,
  void* __restrict__ Cv, long ldc, long szC,
  const float* __restrict__ bias,
  const void* __restrict__ resv, long ldr, long szR, float res_scale,
  const float* __restrict__ gate,
  float alpha, int M, int N, int K, int NX, int NY)
{
  __shared__ alignas(16) u16 shA[128*32];
  __shared__ alignas(16) u16 shB[128*32];
  const int nwg = (int)gridDim.x;
  const int orig = (int)blockIdx.x;
  const int q = nwg>>3, r = nwg&7;
  const int xcd = orig&7, idx = orig>>3;
  const int wg = (xcd<r ? xcd*(q+1) : r*(q+1)+(xcd-r)*q) + idx;
  const int bx = wg % NX; const int t_ = wg / NX;
  const int by = t_ % NY; const int z  = t_ / NY;

  A += (long)z*szA; B += (long)z*szB;
  const int tid=threadIdx.x, lane=tid&63, wid=tid>>6;
  const int wr=wid>>1, wc=wid&1;
  const long m0=(long)bx*128, n0=(long)by*128;
  f32x4 acc[4][4];
#pragma unroll
  for(int i=0;i<4;i++)
#pragma unroll
    for(int j=0;j<4;j++){ f32x4 zv={0.f,0.f,0.f,0.f}; acc[i][j]=zv; }

  const int lr = lane>>2, lsl = lane&3;
  const u16* pA[2]; const u16* pB[2]; u16* lA[2]; u16* lB[2];
#pragma unroll
  for(int i=0;i<2;i++){
    int ra = wid*32 + i*16 + lr;
    int kc = (lsl ^ ((ra>>1)&3))*8;
    long gr = m0+ra; if(gr>=M) gr=M-1;
    long gb = n0+ra; if(gb>=N) gb=N-1;
    pA[i] = A + gr*lda + kc;
    pB[i] = B + gb*ldb + kc;
    lA[i] = shA + (wid*32 + i*16)*32;
    lB[i] = shB + (wid*32 + i*16)*32;
  }

  for(int k0=0;k0<K;k0+=32){
    __syncthreads();
#pragma unroll
    for(int i=0;i<2;i++){
      gload16(pA[i]+k0, lA[i]);
      gload16(pB[i]+k0, lB[i]);
    }
    __syncthreads();
    const int ks = lane>>4, rr = lane&15;
    u32x4 av[4], bv[4];
#pragma unroll
    for(int mi=0;mi<4;mi++) av[mi] = ((const u32x4*)shA)[swz((wr*64+mi*16+rr)*4+ks)];
#pragma unroll
    for(int ni=0;ni<4;ni++) bv[ni] = ((const u32x4*)shB)[swz((wc*64+ni*16+rr)*4+ks)];
#pragma unroll
    for(int mi=0;mi<4;mi++)
#pragma unroll
      for(int ni=0;ni<4;ni++)
        asm volatile("v_mfma_f32_16x16x32_bf16 %0, %1, %2, %0"
                     : "+v"(acc[mi][ni]) : "v"(av[mi]), "v"(bv[ni]));
  }
  const float* resf = (const float*)resv + (long)z*szR;
  const u16*   resh = (const u16*)resv   + (long)z*szR;
  float* Cf = (float*)Cv + (long)z*szC;
  u16*   Ch = (u16*)Cv   + (long)z*szC;
  float gv = (FLAGS&F_GATE)? gate[z] : 1.f;
#pragma unroll
  for(int mi=0;mi<4;mi++){
#pragma unroll
    for(int ni=0;ni<4;ni++){
      long c0 = n0 + wc*64 + ni*16 + (lane&15);
      if(c0>=N) continue;
      float bb = (FLAGS&F_BIAS)? bias[c0] : 0.f;
#pragma unroll
      for(int r2=0;r2<4;r2++){
        long rw = m0 + wr*64 + mi*16 + (lane>>4)*4 + r2;
        if(rw>=M) continue;
        float t = acc[mi][ni][r2]*alpha*gv + bb;
        if(FLAGS&F_RES){
          float rvv = (FLAGS&F_RESF32)? resf[rw*ldr+c0] : b2f(resh[rw*ldr+c0]);
          t += res_scale*rvv;
        }
        if(FLAGS&F_GELU) t = 0.5f*t*(1.f+erff(t*0.70710678118654752f));
        if(FLAGS&F_OUTF32) Cf[rw*ldc+c0]=t;
        else               Ch[rw*ldc+c0]=f2b(t);
      }
    }
  }
}

static inline int gpack(int M,int N,int nb,int& NX,int& NY){
  NX=(M+127)/128; NY=(N+127)/128; return NX*NY*nb;
}

// ---------------- 256x256 deep-pipelined GEMM (flattened M, N%256==0) --------
// 512 thr = 8 waves (2M x 4N); BK=64 split in two k-halves; LDS double-buffer
// (128KB); counted vmcnt(4), raw s_barrier (2/K-tile), setprio around MFMA.
// LDS layout per buffer+matrix: [kk][256 rows][32 cols], 16B slots XOR-swizzled
// phys_sl = sl ^ ((row>>1)&3); staged via pre-swizzled GLOBAL source (linear LDS).
template<int FLAGS>
__global__ __launch_bounds__(512,2) void gemm256(
  const u16* __restrict__ A, long lda,
  const u16* __restrict__ B, long ldb,
  u16* __restrict__ C, long ldc,
  const float* __restrict__ bias,
  const u16* __restrict__ res, long ldr,
  const float* __restrict__ gate, const float* __restrict__ scres,
  float irpz, float alpha, int M, int N, int K, int NX)
{
  __shared__ u16 smem[65536];   // A: [0,32768) B: [32768,65536), each 2 bufs x 16384
  const int nwg=(int)gridDim.x, orig=(int)blockIdx.x;
  const int qq=nwg>>3, rr8=nwg&7, xcd=orig&7, idx=orig>>3;
  const int wg=(xcd<rr8? xcd*(qq+1): rr8*(qq+1)+(xcd-rr8)*qq)+idx;
  const int bx=wg%NX, by=wg/NX;
  const long m0=(long)bx*256, n0=(long)by*256;
  const int tid=threadIdx.x, lane=tid&63, wid=tid>>6;
  const int wr=wid>>2, wc=wid&3;

  f32x4 acc[8][4];
#pragma unroll
  for(int i=0;i<8;i++)
#pragma unroll
    for(int j=0;j<4;j++){ f32x4 zv={0.f,0.f,0.f,0.f}; acc[i][j]=zv; }

  // staging sources, pre-swizzled (k-invariant)
  const u16* sA[2][2]; const u16* sB[2][2];
#pragma unroll
  for(int kh=0;kh<2;kh++)
#pragma unroll
    for(int jj=0;jj<2;jj++){
      int s=jj*512+tid, row=s>>2, sl=(s&3)^((s>>3)&3);
      long ar=m0+row; if(ar>=M) ar=M-1;
      long br=n0+row; if(br>=N) br=N-1;
      sA[kh][jj]=A+ar*lda+kh*32+sl*8;
      sB[kh][jj]=B+br*ldb+kh*32+sl*8;
    }
  const int dst0=(wid*64)*8, dst1=(512+wid*64)*8;   // elems within a kh-block
  const int ks=lane>>4, l15=lane&15;
  const int phys=(ks^((l15>>1)&3))*8;
  const int aBase=(wr*128+l15)*32+phys;
  const int bBase=(wc*64 +l15)*32+phys;
  const int NT=K>>6;

#define STG(t,c,kh) { long k0_=(long)(t)*64; \
    gload16(sA[kh][0]+k0_, smem + (c)*16384 + (kh)*8192 + dst0); \
    gload16(sA[kh][1]+k0_, smem + (c)*16384 + (kh)*8192 + dst1); \
    gload16(sB[kh][0]+k0_, smem + 32768 + (c)*16384 + (kh)*8192 + dst0); \
    gload16(sB[kh][1]+k0_, smem + 32768 + (c)*16384 + (kh)*8192 + dst1); }

  STG(0,0,0); STG(0,0,1);
  asm volatile("s_waitcnt vmcnt(4)" ::: "memory");
  __builtin_amdgcn_s_barrier();
  asm volatile("" ::: "memory");

  u32x4 av[4], bv[4];
  for(int t=0;t<NT;++t){
    const int cur=t&1, nxt=cur^1;
    const u16* sa=smem + cur*16384;
    const u16* sb=smem + 32768 + cur*16384;
    const bool pf=(t+1<NT);
    // ---- phase 1 (kk0, mh0): prefetch next kh0; read A-lo + B(kk0); 16 MFMA
    if(pf) STG(t+1,nxt,0);
#pragma unroll
    for(int j=0;j<4;j++) bv[j]=*(const u32x4*)(sb + bBase + j*512);
#pragma unroll
    for(int i=0;i<4;i++) av[i]=*(const u32x4*)(sa + aBase + i*512);
    __builtin_amdgcn_s_setprio(1);
#pragma unroll
    for(int i=0;i<4;i++)
#pragma unroll
      for(int j=0;j<4;j++)
        asm volatile("v_mfma_f32_16x16x32_bf16 %0, %1, %2, %0":"+v"(acc[i][j]):"v"(av[i]),"v"(bv[j]));
    __builtin_amdgcn_s_setprio(0);
    // ---- phase 2 (kk0, mh1)
#pragma unroll
    for(int i=0;i<4;i++) av[i]=*(const u32x4*)(sa + aBase + 2048 + i*512);
    __builtin_amdgcn_s_setprio(1);
#pragma unroll
    for(int i=0;i<4;i++)
#pragma unroll
      for(int j=0;j<4;j++)
        asm volatile("v_mfma_f32_16x16x32_bf16 %0, %1, %2, %0":"+v"(acc[4+i][j]):"v"(av[i]),"v"(bv[j]));
    __builtin_amdgcn_s_setprio(0);
    // ---- boundary 1: need S(t,kh1) resident everywhere
    if(pf) asm volatile("s_waitcnt vmcnt(4)" ::: "memory");
    else   asm volatile("s_waitcnt vmcnt(0)" ::: "memory");
    __builtin_amdgcn_s_barrier();
    asm volatile("" ::: "memory");
    // ---- phase 3 (kk1, mh0): prefetch next kh1; read A-lo + B(kk1); 16 MFMA
    if(pf) STG(t+1,nxt,1);
#pragma unroll
    for(int j=0;j<4;j++) bv[j]=*(const u32x4*)(sb + 8192 + bBase + j*512);
#pragma unroll
    for(int i=0;i<4;i++) av[i]=*(const u32x4*)(sa + 8192 + aBase + i*512);
    __builtin_amdgcn_s_setprio(1);
#pragma unroll
    for(int i=0;i<4;i++)
#pragma unroll
      for(int j=0;j<4;j++)
        asm volatile("v_mfma_f32_16x16x32_bf16 %0, %1, %2, %0":"+v"(acc[i][j]):"v"(av[i]),"v"(bv[j]));
    __builtin_amdgcn_s_setprio(0);
    // ---- phase 4 (kk1, mh1)
#pragma unroll
    for(int i=0;i<4;i++) av[i]=*(const u32x4*)(sa + 8192 + aBase + 2048 + i*512);
    __builtin_amdgcn_s_setprio(1);
#pragma unroll
    for(int i=0;i<4;i++)
#pragma unroll
      for(int j=0;j<4;j++)
        asm volatile("v_mfma_f32_16x16x32_bf16 %0, %1, %2, %0":"+v"(acc[4+i][j]):"v"(av[i]),"v"(bv[j]));
    __builtin_amdgcn_s_setprio(0);
    // ---- boundary 2: need S(t+1,kh0) resident everywhere
    if(pf) asm volatile("s_waitcnt vmcnt(4)" ::: "memory");
    else   asm volatile("s_waitcnt vmcnt(0)" ::: "memory");
    __builtin_amdgcn_s_barrier();
    asm volatile("" ::: "memory");
  }
#undef STG

#pragma unroll
  for(int mf=0;mf<8;mf++){
#pragma unroll
    for(int j=0;j<4;j++){
      long c0 = n0 + wc*64 + j*16 + l15;
      float bb=(FLAGS&F_BIAS)? bias[c0]:0.f;
      int cg=((int)(c0>>8))/3;     // c0/768
#pragma unroll
      for(int r2=0;r2<4;r2++){
        long rw = m0 + wr*128 + mf*16 + ks*4 + r2;
        if(rw>=M) continue;
        float t=acc[mf][j][r2]*alpha;
        if(FLAGS&(F_GATE|F_SCRES)){
          int z=(int)(((float)rw+0.5f)*irpz);
          if(FLAGS&F_GATE) t*=gate[z];
          if(FLAGS&F_SCRES) t += scres[z*4+cg]*b2f(res[rw*ldr+c0]);
        } else if(FLAGS&F_RES){
          t += b2f(res[rw*ldr+c0]);
        }
        t+=bb;
        if(FLAGS&F_GELU) t=0.5f*t*(1.f+erff(t*0.70710678118654752f));
        C[rw*ldc+c0]=f2b(t);
      }
    }
  }
}

extern "C" void kernel_launch(void* const* d_in, const int* in_sizes, int n_in,
                              void* d_out, int out_size, void* d_ws, size_t ws_size,
                              hipStream_t stream){
  const int BNr=16*577;            // 9232 rows
  const float* x      = (const float*)d_in[0];
  const float* ln1_g  = (const float*)d_in[1];
  const float* ln1_b  = (const float*)d_in[2];
  const float* ad_ln_g= (const float*)d_in[3];
  const float* ad_ln_b= (const float*)d_in[4];
  const float* ad_w   = (const float*)d_in[5];
  const float* w_qkv  = (const float*)d_in[6];
  const float* w_proj = (const float*)d_in[7];
  const float* b_proj = (const float*)d_in[8];
  const float* ln2_g  = (const float*)d_in[9];
  const float* ln2_b  = (const float*)d_in[10];
  const float* fc1_w  = (const float*)d_in[11];
  const float* fc1_b  = (const float*)d_in[12];
  const float* fc2_w  = (const float*)d_in[13];
  const float* fc2_b  = (const float*)d_in[14];
  const float* r_ln_g = (const float*)d_in[15];
  const float* r_ln_b = (const float*)d_in[16];
  const float* r_proj_w=(const float*)d_in[17];
  const float* r_proj_b=(const float*)d_in[18];
  const float* r_gate_w=(const float*)d_in[19];
  const float* r_gate_b=(const float*)d_in[20];
  const float* r_scale =(const float*)d_in[21];
  const float* d_ln_g = (const float*)d_in[22];
  const float* d_ln_b = (const float*)d_in[23];
  const float* d_outw = (const float*)d_in[24];
  const float* d_gate_w=(const float*)d_in[25];
  const float* d_gate_b=(const float*)d_in[26];

  char* ws=(char*)d_ws;
  size_t off=0;
  auto take=[&](size_t nb){ size_t r=off; off=(off+nb+255)&~(size_t)255; return r; };
  auto al  =[&](size_t v){ return (v+255)&~(size_t)255; };
  const size_t o_qkvT = take((size_t)2304*768*2);
  const size_t o_adT  = take((size_t)768*768*2);
  const size_t o_projT= take((size_t)768*768*2);
  const size_t o_fc1T = take((size_t)3072*768*2);
  const size_t o_fc2T = take((size_t)768*3072*2);
  const size_t o_doutT= take((size_t)3072*3072*2);
  const size_t o_x2   = take((size_t)BNr*768*4);       // f32
  const size_t o_hid  = take((size_t)BNr*3072*2);
  const size_t o_stats= take((size_t)BNr*2*4);
  const size_t o_rn   = take((size_t)BNr*4);
  const size_t o_sum  = take((size_t)16*6144*4);
  const size_t o_scalef=take(64*4);
  const size_t o_dg   = take(64);
  const size_t o_h    = take((size_t)BNr*768*2);
  const size_t o_lnh  = take((size_t)BNr*768*2);
  const size_t o_metric=take((size_t)BNr*768*2);
  const size_t o_qk   = take((size_t)BNr*1536*2);
  const size_t o_v    = take((size_t)BNr*768*2);
  const size_t o_qh   = take((size_t)192*577*64*2);
  const size_t o_kh   = take((size_t)192*577*64*2);
  const size_t o_vT   = take((size_t)192*64*608*2);
  (void)o_v; (void)o_vT; (void)ws_size; (void)in_sizes; (void)n_in; (void)out_size;
  const size_t o_S    = o_qk;
  const size_t o_aoh  = o_metric;
  const size_t o_aout = o_h;
  const size_t o_h2   = o_lnh;
  const size_t o_dn   = o_h;
  const size_t o_aff  = al(o_dn + (size_t)BNr*3072*2);
  const size_t o_dnTb = al(o_aff + (size_t)16*577*608*2);
  const size_t o_diff = al(o_dnTb + (size_t)4*3072*608*2);
  const size_t o_hact = o_dn;

  u16* qkvT=(u16*)(ws+o_qkvT); u16* adT=(u16*)(ws+o_adT); u16* projT=(u16*)(ws+o_projT);
  u16* fc1T=(u16*)(ws+o_fc1T); u16* fc2T=(u16*)(ws+o_fc2T); u16* doutT=(u16*)(ws+o_doutT);
  float* x2=(float*)(ws+o_x2); u16* hid=(u16*)(ws+o_hid);
  float* stats=(float*)(ws+o_stats); float* rn=(float*)(ws+o_rn);
  float* summ=(float*)(ws+o_sum); float* scalef=(float*)(ws+o_scalef); float* dgate=(float*)(ws+o_dg);
  u16* hbuf=(u16*)(ws+o_h); u16* lnh=(u16*)(ws+o_lnh); u16* metric=(u16*)(ws+o_metric);
  u16* qkbuf=(u16*)(ws+o_qk); u16* vbuf=(u16*)(ws+o_v);
  u16* qh=(u16*)(ws+o_qh); u16* kh=(u16*)(ws+o_kh); u16* vT=(u16*)(ws+o_vT);
  u16* Sc=(u16*)(ws+o_S); u16* aoh=(u16*)(ws+o_aoh); u16* aout=(u16*)(ws+o_aout);
  u16* h2=(u16*)(ws+o_h2);
  u16* dn=(u16*)(ws+o_dn); u16* aff=(u16*)(ws+o_aff); u16* dnTb=(u16*)(ws+o_dnTb);
  u16* diff=(u16*)(ws+o_diff); u16* hact=(u16*)(ws+o_hact);

  dim3 blk(256), blk5(512);
  int NX, NY, ng;
  // ---- weight transposes f32 -> bf16 [N,K]
  transpose_pad<float><<<dim3(72,24,1),blk,0,stream>>>(w_qkv, qkvT, 768,2304,768, 0,0);
  transpose_pad<float><<<dim3(24,24,1),blk,0,stream>>>(ad_w,  adT,  768,768, 768, 0,0);
  transpose_pad<float><<<dim3(24,24,1),blk,0,stream>>>(w_proj,projT,768,768, 768, 0,0);
  transpose_pad<float><<<dim3(96,24,1),blk,0,stream>>>(fc1_w, fc1T, 768,3072,768, 0,0);
  transpose_pad<float><<<dim3(24,96,1),blk,0,stream>>>(fc2_w, fc2T, 3072,768,3072,0,0);
  transpose_pad<float><<<dim3(96,96,1),blk,0,stream>>>(d_outw,doutT,3072,3072,3072,0,0);
  // ---- attention block
  ln_rows<float><<<BNr,blk,0,stream>>>(x, ln1_g, ln1_b, hbuf, 768);
  ln_rows<u16>  <<<BNr,blk,0,stream>>>(hbuf, ad_ln_g, ad_ln_b, lnh, 768);
  ng=gpack(BNr,768,1,NX,NY);
  gemm_bt<F_RES><<<ng,blk,0,stream>>>(lnh,768,0, adT,768,0, metric,768,0,
      nullptr, hbuf,768,0, 1.f, nullptr, 1.f, BNr,768,768, NX,NY);
  gemm256<0><<<dim3(37*6),blk5,0,stream>>>(metric,768, qkvT,768, qkbuf,1536,
      nullptr, nullptr,0, nullptr,nullptr, 0.f, 1.f, BNr,1536,768, 37);
  ng=gpack(BNr,768,1,NX,NY);
  gemm_bt<0><<<ng,blk,0,stream>>>(hbuf,768,0, qkvT+(size_t)1536*768,768,0, vbuf,768,0,
      nullptr, nullptr,0,0,0.f, nullptr, 1.f, BNr,768,768, NX,NY);
  split_heads<<<3462,blk,0,stream>>>(qkbuf, qh, kh);
  make_vT<<<29184,blk,0,stream>>>(vbuf, vT);
  for(int c=0;c<6;c++){
    const u16* qc=qh+(size_t)c*32*577*64;
    const u16* kc=kh+(size_t)c*32*577*64;
    ng=gpack(577,577,32,NX,NY);
    gemm_bt<0><<<ng,blk,0,stream>>>(qc,64,(long)577*64, kc,64,(long)577*64,
        Sc,608,(long)577*608, nullptr, nullptr,0,0,0.f, nullptr, 0.125f, 577,577,64, NX,NY);
    softmax_rows<<<32*577,blk,0,stream>>>(Sc,577,608, nullptr,577, 1.f);
    ng=gpack(577,64,32,NX,NY);
    gemm_bt<0><<<ng,blk,0,stream>>>(Sc,608,(long)577*608, vT+(size_t)c*32*64*608,608,(long)64*608,
        aoh+(size_t)c*32*577*64,64,(long)577*64, nullptr, nullptr,0,0,0.f, nullptr, 1.f, 577,64,608, NX,NY);
  }
  merge_heads<<<3462,blk,0,stream>>>(aoh, aout);
  ng=gpack(BNr,768,1,NX,NY);
  gemm_bt<F_RES|F_BIAS|F_RESF32|F_OUTF32><<<ng,blk,0,stream>>>(aout,768,0, projT,768,0,
      x2,768,0, b_proj, x,768,0, 1.f, nullptr, 1.f, BNr,768,768, NX,NY);
  // ---- MLP front
  ln_rows<float><<<BNr,blk,0,stream>>>(x2, ln2_g, ln2_b, h2, 768);
  gemm256<F_BIAS><<<dim3(37*12),blk5,0,stream>>>(h2,768, fc1T,768, hid,3072,
      fc1_b, nullptr,0, nullptr,nullptr, 0.f, 1.f, BNr,3072,768, 37);
  // ---- router (on UNSCALED hid; scale fused downstream)
  row_stats<<<BNr,blk,0,stream>>>(hid, stats, 3072);
  summary_kernel<<<dim3(12,16),blk,0,stream>>>(hid, stats, r_ln_g, r_ln_b, summ);
  router_kernel<<<16,blk,0,stream>>>(summ, r_proj_w, r_proj_b, r_gate_w, r_gate_b, r_scale, scalef);
  // ---- token diffusion (dn = LN(hid*scale))
  dn_kernel<<<BNr,blk,0,stream>>>(hid, d_ln_g, d_ln_b, scalef, dn, rn);
  dgate_kernel<<<16,blk,0,stream>>>(dn, d_gate_w, d_gate_b, dgate);
  ng=gpack(577,577,16,NX,NY);
  gemm_bt<0><<<ng,blk,0,stream>>>(dn,3072,(long)577*3072, dn,3072,(long)577*3072,
      aff,608,(long)577*608, nullptr, nullptr,0,0,0.f, nullptr, 1.f, 577,577,3072, NX,NY);
  softmax_rows<<<BNr,blk,0,stream>>>(aff,577,608, rn,577, 0.01804219634f);
  for(int g4=0; g4<4; ++g4){
    transpose_pad<u16><<<dim3(96,19,4),blk,0,stream>>>(dn+(size_t)g4*4*577*3072, dnTb,
        577,3072,608, (long)577*3072, (long)3072*608);
    ng=gpack(577,3072,4,NX,NY);
    gemm_bt<F_RES><<<ng,blk,0,stream>>>(aff+(size_t)g4*4*577*608,608,(long)577*608,
        dnTb,608,(long)3072*608, diff+(size_t)g4*4*577*3072,3072,(long)577*3072,
        nullptr, dn+(size_t)g4*4*577*3072,3072,(long)577*3072, -1.f, nullptr, 1.f, 577,3072,608, NX,NY);
  }
  // dmix: hact = gelu(dgate[z]*(diff@doutT) + scale[z,cg]*hid)   (flattened M)
  gemm256<F_GELU|F_GATE|F_SCRES><<<dim3(37*12),blk5,0,stream>>>(diff,3072, doutT,3072,
      hact,3072, nullptr, hid,3072, dgate, scalef, 1.f/577.f, 1.f, BNr,3072,3072, 37);
  // ---- fc2 + final residual (f32 out)
  ng=gpack(BNr,768,1,NX,NY);
  gemm_bt<F_RES|F_BIAS|F_RESF32|F_OUTF32><<<ng,blk,0,stream>>>(hact,3072,0,
      fc2T,3072,0, d_out,768,0, fc2_b, x2,768,0, 1.f, nullptr, 1.f, BNr,768,3072, NX,NY);
}

// Round 4
// 1508.949 us; speedup vs baseline: 1.1055x; 1.0087x over previous
//
#include <hip/hip_runtime.h>
#include <math.h>

typedef unsigned short u16;
typedef unsigned int   u32;
typedef __attribute__((ext_vector_type(4))) float f32x4;
typedef __attribute__((ext_vector_type(4))) u32   u32x4;

#define DEV __device__ __forceinline__
#define AS1 __attribute__((address_space(1)))
#define AS3 __attribute__((address_space(3)))

DEV float b2f(u16 u){ u32 x = ((u32)u)<<16; float f; __builtin_memcpy(&f,&x,4); return f; }
DEV u16 f2b(float f){ u32 x; __builtin_memcpy(&x,&f,4); u32 r = x + 0x7FFFu + ((x>>16)&1u); return (u16)(r>>16); }

DEV float ldf(const float* p, long i){ return p[i]; }
DEV float ldf(const u16*   p, long i){ return b2f(p[i]); }

DEV void gload16(const u16* g, u16* l){
  __builtin_amdgcn_global_load_lds((const AS1 u32*)(const void*)g,
                                   (AS3 u32*)(void*)l, 16, 0, 0);
}

DEV float wave_sum(float v){
#pragma unroll
  for(int o=32;o;o>>=1) v += __shfl_down(v,o,64);
  return v;
}
DEV float wave_max(float v){
#pragma unroll
  for(int o=32;o;o>>=1) v = fmaxf(v, __shfl_down(v,o,64));
  return v;
}
// blockDim.x == 256 assumed in block_sum/block_max users.
DEV float block_sum(float v, float* tmp){
  v = wave_sum(v);
  if((threadIdx.x&63)==0) tmp[threadIdx.x>>6]=v;
  __syncthreads();
  float r = tmp[0]+tmp[1]+tmp[2]+tmp[3];
  __syncthreads();
  return r;
}
DEV float block_max(float v, float* tmp){
  v = wave_max(v);
  if((threadIdx.x&63)==0) tmp[threadIdx.x>>6]=v;
  __syncthreads();
  float r = fmaxf(fmaxf(tmp[0],tmp[1]),fmaxf(tmp[2],tmp[3]));
  __syncthreads();
  return r;
}

// ---------------- transpose (+K-pad with zeros), out always bf16 -------------
template<typename TI>
__global__ void transpose_pad(const TI* __restrict__ in, u16* __restrict__ out,
                              int R, int C, int Rpad, long strideI, long strideO){
  __shared__ u16 t[32][33];
  in  += (long)blockIdx.z*strideI;
  out += (long)blockIdx.z*strideO;
  int tx = threadIdx.x & 31, ty = threadIdx.x >> 5;
  int bc = blockIdx.x*32, br = blockIdx.y*32;
#pragma unroll
  for(int i=0;i<32;i+=8){
    int r = br+ty+i, c = bc+tx;
    float v = (r<R && c<C) ? ldf(in,(long)r*C+c) : 0.f;
    t[ty+i][tx] = f2b(v);
  }
  __syncthreads();
#pragma unroll
  for(int i=0;i<32;i+=8){
    int c = bc+ty+i, r = br+tx;
    if(c<C && r<Rpad) out[(long)c*Rpad + r] = t[tx][ty+i];
  }
}

// ---------------- LayerNorm rows ---------------------------------------------
template<typename TI>
__global__ void ln_rows(const TI* __restrict__ x, const float* __restrict__ g,
                        const float* __restrict__ b, u16* __restrict__ y, int W){
  __shared__ float tmp[4];
  long base=(long)blockIdx.x*W;
  float s=0.f, ss=0.f;
  for(int c=threadIdx.x;c<W;c+=256){ float v=ldf(x,base+c); s+=v; ss+=v*v; }
  s=block_sum(s,tmp); ss=block_sum(ss,tmp);
  float mu=s/W;
  float rstd=rsqrtf(fmaxf(ss/W-mu*mu,0.f)+1e-5f);
  for(int c=threadIdx.x;c<W;c+=256){
    float v=ldf(x,base+c);
    y[base+c]=f2b((v-mu)*rstd*g[c]+b[c]);
  }
}

__global__ void row_stats(const u16* __restrict__ x, float* __restrict__ stats, int W){
  __shared__ float tmp[4];
  long base=(long)blockIdx.x*W;
  float s=0.f,ss=0.f;
  for(int c=threadIdx.x;c<W;c+=256){ float v=b2f(x[base+c]); s+=v; ss+=v*v; }
  s=block_sum(s,tmp); ss=block_sum(ss,tmp);
  if(threadIdx.x==0){
    float mu=s/W;
    stats[2*(long)blockIdx.x]=mu;
    stats[2*(long)blockIdx.x+1]=rsqrtf(fmaxf(ss/W-mu*mu,0.f)+1e-5f);
  }
}

// dn = LN(hid*scale; d_ln), rn = 1/max(||dn||,1e-12)  (router scale fused in)
__global__ void dn_kernel(const u16* __restrict__ x, const float* __restrict__ g,
                          const float* __restrict__ b, const float* __restrict__ scalef,
                          u16* __restrict__ dn, float* __restrict__ rn){
  const int W=3072;
  __shared__ float tmp[4];
  __shared__ u16 rowb[3072];
  long row=(long)blockIdx.x;
  long base=row*(long)W;
  int bz=(int)(row/577);
  float s=0.f,ss=0.f;
  for(int c=threadIdx.x;c<W;c+=256){
    float sc=scalef[bz*4 + ((c>>8)/3)];
    float v=b2f(x[base+c])*sc;
    rowb[c]=f2b(v);
    s+=v; ss+=v*v;
  }
  s=block_sum(s,tmp); ss=block_sum(ss,tmp);
  float mu=s/W;
  float rstd=rsqrtf(fmaxf(ss/W-mu*mu,0.f)+1e-5f);
  float sq=0.f;
  for(int c=threadIdx.x;c<W;c+=256){
    float v=(b2f(rowb[c])-mu)*rstd*g[c]+b[c];
    sq+=v*v;
  }
  sq=block_sum(sq,tmp);
  float r=1.f/fmaxf(sqrtf(sq),1e-12f);
  for(int c=threadIdx.x;c<W;c+=256){
    float v=(b2f(rowb[c])-mu)*rstd*g[c]+b[c];
    dn[base+c]=f2b(v);
  }
  if(threadIdx.x==0) rn[blockIdx.x]=r;
}

// ------------- softmax over rows (in-place bf16), optional row/col scaling ---
__global__ void softmax_rows(u16* __restrict__ S, int W, int Wp,
                             const float* __restrict__ rs, int rpb, float alpha){
  __shared__ float tmp[4];
  long row = blockIdx.x;
  u16* p = S + row*(long)Wp;
  float rowscale = alpha;
  const float* rsb = nullptr;
  if(rs){ long bt=row/rpb; int m=(int)(row%rpb); rsb = rs + bt*(long)rpb; rowscale *= rsb[m]; }
  float mx=-3e38f;
  for(int c=threadIdx.x;c<W;c+=256){
    float v=b2f(p[c])*rowscale; if(rs) v*=rsb[c];
    mx=fmaxf(mx,v);
  }
  mx=block_max(mx,tmp);
  float sm=0.f;
  for(int c=threadIdx.x;c<W;c+=256){
    float v=b2f(p[c])*rowscale; if(rs) v*=rsb[c];
    sm+=__expf(v-mx);
  }
  sm=block_sum(sm,tmp);
  float inv=1.f/sm;
  for(int c=threadIdx.x;c<W;c+=256){
    float v=b2f(p[c])*rowscale; if(rs) v*=rsb[c];
    p[c]=f2b(__expf(v-mx)*inv);
  }
  for(int c=W+threadIdx.x;c<Wp;c+=256) p[c]=0;
}

// ---------------- attention head reshapes ------------------------------------
__global__ void split_heads(const u16* __restrict__ qk, u16* __restrict__ qh, u16* __restrict__ kh){
  int i = blockIdx.x*256+threadIdx.x;
  if(i >= 16*577*12*8) return;
  int dv = i&7; int h=(i>>3)%12; int bn=i/96;
  int b=bn/577, n=bn%577;
  long src=(long)bn*1536 + h*64 + dv*8;
  long dst=((long)((b*12+h)*577+n))*64 + dv*8;
  *(u32x4*)(qh+dst) = *(const u32x4*)(qk+src);
  *(u32x4*)(kh+dst) = *(const u32x4*)(qk+src+768);
}
__global__ void merge_heads(const u16* __restrict__ aoh, u16* __restrict__ aout){
  int i = blockIdx.x*256+threadIdx.x;
  if(i >= 16*577*12*8) return;
  int dv=i&7; int h=(i>>3)%12; int bn=i/96;
  int b=bn/577, n=bn%577;
  long dst=(long)bn*768 + h*64 + dv*8;
  long src=((long)((b*12+h)*577+n))*64 + dv*8;
  *(u32x4*)(aout+dst) = *(const u32x4*)(aoh+src);
}
__global__ void make_vT(const u16* __restrict__ v, u16* __restrict__ vT){
  long i = (long)blockIdx.x*256+threadIdx.x;
  if(i >= (long)192*64*608) return;
  int n=(int)(i%608); long q=i/608; int d=(int)(q&63); int bh=(int)(q>>6);
  int b=bh/12, h=bh%12;
  u16 val=0;
  if(n<577) val = v[((long)(b*577+n))*768 + h*64 + d];
  vT[i]=val;
}

// ---------------- router -----------------------------------------------------
__global__ void summary_kernel(const u16* __restrict__ hid, const float* __restrict__ stats,
                               const float* __restrict__ rg, const float* __restrict__ rb,
                               float* __restrict__ summ){
  int b=blockIdx.y;
  int c=blockIdx.x*256+threadIdx.x;   // grid.x=12 -> c<3072
  const u16* hb=hid+(size_t)b*577*3072;
  const float* st=stats+(size_t)b*577*2;
  float g=rg[c], be=rb[c];
  float cls=(b2f(hb[c])-st[0])*st[1]*g+be;
  float acc=0.f;
  for(int n=1;n<577;n++) acc += (b2f(hb[(size_t)n*3072+c])-st[2*n])*st[2*n+1];
  summ[(size_t)b*6144+c]        = 1.0f*cls;                         // CLS_MIX
  summ[(size_t)b*6144+3072+c]   = 0.5f*(g*(acc*(1.f/576.f))+be);    // MEAN_MIX
}

__global__ void router_kernel(const float* __restrict__ summ, const float* __restrict__ pw,
                              const float* __restrict__ pb, const float* __restrict__ gw,
                              const float* __restrict__ gb, const float* __restrict__ rsc,
                              float* __restrict__ scalef){
  __shared__ float tmp[4];
  int b=blockIdx.x;
  float a0=0,a1=0,a2=0,a3=0,a4=0;
  for(int c=threadIdx.x;c<6144;c+=256){
    float sv=summ[(size_t)b*6144+c];
    a0+=sv*pw[c*4+0]; a1+=sv*pw[c*4+1]; a2+=sv*pw[c*4+2]; a3+=sv*pw[c*4+3];
    a4+=sv*gw[c];
  }
  a0=block_sum(a0,tmp); a1=block_sum(a1,tmp); a2=block_sum(a2,tmp);
  a3=block_sum(a3,tmp); a4=block_sum(a4,tmp);
  if(threadIdx.x==0){
    float l0=a0+pb[0], l1=a1+pb[1], l2=a2+pb[2], l3=a3+pb[3];
    float mx=fmaxf(fmaxf(l0,l1),fmaxf(l2,l3));
    float e0=__expf(l0-mx),e1=__expf(l1-mx),e2=__expf(l2-mx),e3=__expf(l3-mx);
    float s=e0+e1+e2+e3;
    float gate=1.f/(1.f+__expf(-(a4+gb[0])));
    float w0=e0/s,w1=e1/s,w2=e2/s,w3=e3/s;
    scalef[b*4+0]=1.f+gate*rsc[0]*(4.f*w0-1.f);
    scalef[b*4+1]=1.f+gate*rsc[1]*(4.f*w1-1.f);
    scalef[b*4+2]=1.f+gate*rsc[2]*(4.f*w2-1.f);
    scalef[b*4+3]=1.f+gate*rsc[3]*(4.f*w3-1.f);
  }
}

__global__ void dgate_kernel(const u16* __restrict__ dn, const float* __restrict__ gw,
                             const float* __restrict__ gb, float* __restrict__ dgate){
  __shared__ float tmp[4];
  int b=blockIdx.x;
  const u16* row = dn + (size_t)b*577*3072;
  float a=0.f;
  for(int c=threadIdx.x;c<3072;c+=256) a+=b2f(row[c])*gw[c];
  a=block_sum(a,tmp);
  if(threadIdx.x==0) dgate[b]=1.f/(1.f+__expf(-(a+gb[0])));
}

constexpr int F_BIAS=1, F_RES=2, F_GELU=4, F_GATE=8, F_RESF32=16, F_OUTF32=32, F_SCRES=64;

// ---------------- 128x128 batched GEMM (small/batched shapes) ----------------
DEV int swz(int u){ int row=u>>2, sl=u&3; return row*4 + (sl ^ ((row>>1)&3)); }

template<int FLAGS>
__global__ __launch_bounds__(256,2) void gemm_bt(
  const u16* __restrict__ A, long lda, long szA,
  const u16* __restrict__ B, long ldb, long szB,
  void* __restrict__ Cv, long ldc, long szC,
  const float* __restrict__ bias,
  const void* __restrict__ resv, long ldr, long szR, float res_scale,
  const float* __restrict__ gate,
  float alpha, int M, int N, int K, int NX, int NY)
{
  __shared__ alignas(16) u16 shA[128*32];
  __shared__ alignas(16) u16 shB[128*32];
  const int nwg = (int)gridDim.x;
  const int orig = (int)blockIdx.x;
  const int q = nwg>>3, r = nwg&7;
  const int xcd = orig&7, idx = orig>>3;
  const int wg = (xcd<r ? xcd*(q+1) : r*(q+1)+(xcd-r)*q) + idx;
  const int bx = wg % NX; const int t_ = wg / NX;
  const int by = t_ % NY; const int z  = t_ / NY;

  A += (long)z*szA; B += (long)z*szB;
  const int tid=threadIdx.x, lane=tid&63, wid=tid>>6;
  const int wr=wid>>1, wc=wid&1;
  const long m0=(long)bx*128, n0=(long)by*128;
  f32x4 acc[4][4];
#pragma unroll
  for(int i=0;i<4;i++)
#pragma unroll
    for(int j=0;j<4;j++){ f32x4 zv={0.f,0.f,0.f,0.f}; acc[i][j]=zv; }

  const int lr = lane>>2, lsl = lane&3;
  const u16* pA[2]; const u16* pB[2]; u16* lA[2]; u16* lB[2];
#pragma unroll
  for(int i=0;i<2;i++){
    int ra = wid*32 + i*16 + lr;
    int kc = (lsl ^ ((ra>>1)&3))*8;
    long gr = m0+ra; if(gr>=M) gr=M-1;
    long gb = n0+ra; if(gb>=N) gb=N-1;
    pA[i] = A + gr*lda + kc;
    pB[i] = B + gb*ldb + kc;
    lA[i] = shA + (wid*32 + i*16)*32;
    lB[i] = shB + (wid*32 + i*16)*32;
  }

  for(int k0=0;k0<K;k0+=32){
    __syncthreads();
#pragma unroll
    for(int i=0;i<2;i++){
      gload16(pA[i]+k0, lA[i]);
      gload16(pB[i]+k0, lB[i]);
    }
    __syncthreads();
    const int ks = lane>>4, rr = lane&15;
    u32x4 av[4], bv[4];
#pragma unroll
    for(int mi=0;mi<4;mi++) av[mi] = ((const u32x4*)shA)[swz((wr*64+mi*16+rr)*4+ks)];
#pragma unroll
    for(int ni=0;ni<4;ni++) bv[ni] = ((const u32x4*)shB)[swz((wc*64+ni*16+rr)*4+ks)];
#pragma unroll
    for(int mi=0;mi<4;mi++)
#pragma unroll
      for(int ni=0;ni<4;ni++)
        asm volatile("v_mfma_f32_16x16x32_bf16 %0, %1, %2, %0"
                     : "+v"(acc[mi][ni]) : "v"(av[mi]), "v"(bv[ni]));
  }
  const float* resf = (const float*)resv + (long)z*szR;
  const u16*   resh = (const u16*)resv   + (long)z*szR;
  float* Cf = (float*)Cv + (long)z*szC;
  u16*   Ch = (u16*)Cv   + (long)z*szC;
  float gv = (FLAGS&F_GATE)? gate[z] : 1.f;
#pragma unroll
  for(int mi=0;mi<4;mi++){
#pragma unroll
    for(int ni=0;ni<4;ni++){
      long c0 = n0 + wc*64 + ni*16 + (lane&15);
      if(c0>=N) continue;
      float bb = (FLAGS&F_BIAS)? bias[c0] : 0.f;
#pragma unroll
      for(int r2=0;r2<4;r2++){
        long rw = m0 + wr*64 + mi*16 + (lane>>4)*4 + r2;
        if(rw>=M) continue;
        float t = acc[mi][ni][r2]*alpha*gv + bb;
        if(FLAGS&F_RES){
          float rvv = (FLAGS&F_RESF32)? resf[rw*ldr+c0] : b2f(resh[rw*ldr+c0]);
          t += res_scale*rvv;
        }
        if(FLAGS&F_GELU) t = 0.5f*t*(1.f+erff(t*0.70710678118654752f));
        if(FLAGS&F_OUTF32) Cf[rw*ldc+c0]=t;
        else               Ch[rw*ldc+c0]=f2b(t);
      }
    }
  }
}

static inline int gpack(int M,int N,int nb,int& NX,int& NY){
  NX=(M+127)/128; NY=(N+127)/128; return NX*NY*nb;
}

// ---------------- 256x256 8-phase GEMM (m201-style), N%256==0, K%64==0 -------
// 512 thr = 8 waves (2M x 4N). BK=64. LDS 128KB = 2buf x {A,B} x 2 row-halves
// x [128 rows][8 slots][16B], slot swizzle phys = s ^ (row&7), staged linearly
// via pre-swizzled GLOBAL source. Per K-tile: 4 phases, each {stage 1 half-tile
// || ds_read subtile -> barrier -> 16 MFMA (setprio) -> barrier}. vmcnt(6) only
// at phase 4 (3 half-tiles in flight); vmcnt(0) only in tail tiles.
template<int FLAGS>
__global__ __launch_bounds__(512,2) void gemm256(
  const u16* __restrict__ A, long lda,
  const u16* __restrict__ B, long ldb,
  u16* __restrict__ C, long ldc,
  const float* __restrict__ bias,
  const u16* __restrict__ res, long ldr,
  const float* __restrict__ gate, const float* __restrict__ scres,
  float irpz, float alpha, int M, int N, int K, int NX)
{
  __shared__ alignas(16) u16 smem[65536];
  char* sm=(char*)smem;
  const int nwg=(int)gridDim.x, orig=(int)blockIdx.x;
  const int qq=nwg>>3, rr8=nwg&7, xcd=orig&7, idx=orig>>3;
  const int wg=(xcd<rr8? xcd*(qq+1): rr8*(qq+1)+(xcd-rr8)*qq)+idx;
  const int bx=wg%NX, by=wg/NX;
  const long m0=(long)bx*256, n0=(long)by*256;
  const int tid=threadIdx.x, lane=tid&63, wid=tid>>6;
  const int wr=wid>>2, wc=wid&3, l15=lane&15, ks=lane>>4;

  f32x4 acc[8][4];
#pragma unroll
  for(int i=0;i<8;i++)
#pragma unroll
    for(int j=0;j<4;j++){ f32x4 zv={0.f,0.f,0.f,0.f}; acc[i][j]=zv; }

  // staging sources (k-invariant, pre-swizzled cols), linear LDS dests
  const u16 *sA[2][2], *sB[2][2];   // [half][j]
  int dstj[2];
#pragma unroll
  for(int j=0;j<2;j++){
    int u=j*512+tid, row=u>>3;
    long co=(long)(((u&7)^(row&7))*8);
    dstj[j]=u*16;
#pragma unroll
    for(int h=0;h<2;h++){
      long gr=m0+h*128+row; if(gr>=M) gr=M-1;
      long gb=n0+h*128+row; if(gb>=N) gb=N-1;
      sA[h][j]=A+gr*lda+co;
      sB[h][j]=B+gb*ldb+co;
    }
  }
  // ds_read bases (bytes within one 64KB buffer)
  int xsl[2]; xsl[0]=((ks^(l15&7))<<4); xsl[1]=(((4+ks)^(l15&7))<<4);
  const int arow = wr*16384 + l15*128;                 // A at offset 0
  int brow[4];
#pragma unroll
  for(int nj=0;nj<4;nj++){ int n=wc*64+nj*16; brow[nj]=32768+(n>>7)*16384+((n&127)+l15)*128; }
  const int NT=K>>6;

#define STG(P,mat,h,kt,bf) { \
  gload16(P[h][0]+(long)(kt)*64,(u16*)(sm+(bf)*65536+(mat)*32768+(h)*16384+dstj[0])); \
  gload16(P[h][1]+(long)(kt)*64,(u16*)(sm+(bf)*65536+(mat)*32768+(h)*16384+dstj[1])); }
#define BAR() { asm volatile("":::"memory"); __builtin_amdgcn_s_barrier(); asm volatile("":::"memory"); }
#define MFMA16(A0,KB) { \
  __builtin_amdgcn_s_setprio(1); \
  _Pragma("unroll") for(int i_=0;i_<4;i_++) \
  _Pragma("unroll") for(int j_=0;j_<4;j_++) \
    asm volatile("v_mfma_f32_16x16x32_bf16 %0, %1, %2, %0" \
                 :"+v"(acc[(A0)+i_][j_]):"v"(av[i_]),"v"(bv[KB][j_])); \
  __builtin_amdgcn_s_setprio(0); }

  // prologue: all 4 halves of tile0 (order B0,B1,A0,A1), first 3 of tile1
  STG(sB,1,0,0,0); STG(sB,1,1,0,0); STG(sA,0,0,0,0); STG(sA,0,1,0,0);
  if(NT>1){ STG(sB,1,0,1,1); STG(sB,1,1,1,1); STG(sA,0,0,1,1); }
  if(NT>1) asm volatile("s_waitcnt vmcnt(6)":::"memory");
  else     asm volatile("s_waitcnt vmcnt(0)":::"memory");
  BAR();

  u32x4 av[4], bv[2][4];
  for(int t=0;t<NT;++t){
    const int cur=t&1, nxt=cur^1;
    const char* bp = sm + cur*65536;
    // phase 1: stage A1(t+1)->nxt; read all B (both kk) + A mh0 kk0; MFMA Q(0,0)
    if(t+1<NT) STG(sA,0,1,t+1,nxt);
#pragma unroll
    for(int kk=0;kk<2;kk++)
#pragma unroll
      for(int nj=0;nj<4;nj++) bv[kk][nj]=*(const u32x4*)(bp+brow[nj]+xsl[kk]);
#pragma unroll
    for(int i=0;i<4;i++) av[i]=*(const u32x4*)(bp+arow+i*2048+xsl[0]);
    BAR();
    MFMA16(0,0);
    BAR();
    // phase 2: stage B0(t+2)->cur; read A mh1 kk0; MFMA Q(1,0)
    if(t+2<NT) STG(sB,1,0,t+2,cur);
#pragma unroll
    for(int i=0;i<4;i++) av[i]=*(const u32x4*)(bp+arow+(4+i)*2048+xsl[0]);
    BAR();
    MFMA16(4,0);
    BAR();
    // phase 3: stage B1(t+2)->cur; read A mh0 kk1; MFMA Q(0,1)
    if(t+2<NT) STG(sB,1,1,t+2,cur);
#pragma unroll
    for(int i=0;i<4;i++) av[i]=*(const u32x4*)(bp+arow+i*2048+xsl[1]);
    BAR();
    MFMA16(0,1);
    BAR();
    // phase 4: stage A0(t+2)->cur; read A mh1 kk1; counted vmcnt; MFMA Q(1,1)
    if(t+2<NT) STG(sA,0,0,t+2,cur);
#pragma unroll
    for(int i=0;i<4;i++) av[i]=*(const u32x4*)(bp+arow+(4+i)*2048+xsl[1]);
    if(t+2<NT) asm volatile("s_waitcnt vmcnt(6)":::"memory");
    else       asm volatile("s_waitcnt vmcnt(0)":::"memory");
    BAR();
    MFMA16(4,1);
    BAR();
  }
#undef STG
#undef BAR
#undef MFMA16

#pragma unroll
  for(int mf=0;mf<8;mf++){
#pragma unroll
    for(int j=0;j<4;j++){
      long c0 = n0 + wc*64 + j*16 + l15;
      float bb=(FLAGS&F_BIAS)? bias[c0]:0.f;
      int cg=((int)(c0>>8))/3;     // c0/768
#pragma unroll
      for(int r2=0;r2<4;r2++){
        long rw = m0 + wr*128 + mf*16 + ks*4 + r2;
        if(rw>=M) continue;
        float t=acc[mf][j][r2]*alpha;
        if(FLAGS&(F_GATE|F_SCRES)){
          int z=(int)(((float)rw+0.5f)*irpz);
          if(FLAGS&F_GATE) t*=gate[z];
          if(FLAGS&F_SCRES) t += scres[z*4+cg]*b2f(res[rw*ldr+c0]);
        } else if(FLAGS&F_RES){
          t += b2f(res[rw*ldr+c0]);
        }
        t+=bb;
        if(FLAGS&F_GELU) t=0.5f*t*(1.f+erff(t*0.70710678118654752f));
        C[rw*ldc+c0]=f2b(t);
      }
    }
  }
}

extern "C" void kernel_launch(void* const* d_in, const int* in_sizes, int n_in,
                              void* d_out, int out_size, void* d_ws, size_t ws_size,
                              hipStream_t stream){
  const int BNr=16*577;            // 9232 rows
  const float* x      = (const float*)d_in[0];
  const float* ln1_g  = (const float*)d_in[1];
  const float* ln1_b  = (const float*)d_in[2];
  const float* ad_ln_g= (const float*)d_in[3];
  const float* ad_ln_b= (const float*)d_in[4];
  const float* ad_w   = (const float*)d_in[5];
  const float* w_qkv  = (const float*)d_in[6];
  const float* w_proj = (const float*)d_in[7];
  const float* b_proj = (const float*)d_in[8];
  const float* ln2_g  = (const float*)d_in[9];
  const float* ln2_b  = (const float*)d_in[10];
  const float* fc1_w  = (const float*)d_in[11];
  const float* fc1_b  = (const float*)d_in[12];
  const float* fc2_w  = (const float*)d_in[13];
  const float* fc2_b  = (const float*)d_in[14];
  const float* r_ln_g = (const float*)d_in[15];
  const float* r_ln_b = (const float*)d_in[16];
  const float* r_proj_w=(const float*)d_in[17];
  const float* r_proj_b=(const float*)d_in[18];
  const float* r_gate_w=(const float*)d_in[19];
  const float* r_gate_b=(const float*)d_in[20];
  const float* r_scale =(const float*)d_in[21];
  const float* d_ln_g = (const float*)d_in[22];
  const float* d_ln_b = (const float*)d_in[23];
  const float* d_outw = (const float*)d_in[24];
  const float* d_gate_w=(const float*)d_in[25];
  const float* d_gate_b=(const float*)d_in[26];

  char* ws=(char*)d_ws;
  size_t off=0;
  auto take=[&](size_t nb){ size_t r=off; off=(off+nb+255)&~(size_t)255; return r; };
  auto al  =[&](size_t v){ return (v+255)&~(size_t)255; };
  const size_t o_qkvT = take((size_t)2304*768*2);
  const size_t o_adT  = take((size_t)768*768*2);
  const size_t o_projT= take((size_t)768*768*2);
  const size_t o_fc1T = take((size_t)3072*768*2);
  const size_t o_fc2T = take((size_t)768*3072*2);
  const size_t o_doutT= take((size_t)3072*3072*2);
  const size_t o_x2   = take((size_t)BNr*768*4);       // f32
  const size_t o_hid  = take((size_t)BNr*3072*2);
  const size_t o_stats= take((size_t)BNr*2*4);
  const size_t o_rn   = take((size_t)BNr*4);
  const size_t o_sum  = take((size_t)16*6144*4);
  const size_t o_scalef=take(64*4);
  const size_t o_dg   = take(64);
  const size_t o_h    = take((size_t)BNr*768*2);
  const size_t o_lnh  = take((size_t)BNr*768*2);
  const size_t o_metric=take((size_t)BNr*768*2);
  const size_t o_qk   = take((size_t)BNr*1536*2);
  const size_t o_v    = take((size_t)BNr*768*2);
  const size_t o_qh   = take((size_t)192*577*64*2);
  const size_t o_kh   = take((size_t)192*577*64*2);
  const size_t o_vT   = take((size_t)192*64*608*2);
  (void)o_v; (void)o_vT; (void)ws_size; (void)in_sizes; (void)n_in; (void)out_size;
  const size_t o_S    = o_qk;
  const size_t o_aoh  = o_metric;
  const size_t o_aout = o_h;
  const size_t o_h2   = o_lnh;
  const size_t o_dn   = o_h;
  const size_t o_aff  = al(o_dn + (size_t)BNr*3072*2);
  const size_t o_dnTb = al(o_aff + (size_t)16*577*608*2);
  const size_t o_diff = al(o_dnTb + (size_t)4*3072*608*2);
  const size_t o_hact = o_dn;

  u16* qkvT=(u16*)(ws+o_qkvT); u16* adT=(u16*)(ws+o_adT); u16* projT=(u16*)(ws+o_projT);
  u16* fc1T=(u16*)(ws+o_fc1T); u16* fc2T=(u16*)(ws+o_fc2T); u16* doutT=(u16*)(ws+o_doutT);
  float* x2=(float*)(ws+o_x2); u16* hid=(u16*)(ws+o_hid);
  float* stats=(float*)(ws+o_stats); float* rn=(float*)(ws+o_rn);
  float* summ=(float*)(ws+o_sum); float* scalef=(float*)(ws+o_scalef); float* dgate=(float*)(ws+o_dg);
  u16* hbuf=(u16*)(ws+o_h); u16* lnh=(u16*)(ws+o_lnh); u16* metric=(u16*)(ws+o_metric);
  u16* qkbuf=(u16*)(ws+o_qk); u16* vbuf=(u16*)(ws+o_v);
  u16* qh=(u16*)(ws+o_qh); u16* kh=(u16*)(ws+o_kh); u16* vT=(u16*)(ws+o_vT);
  u16* Sc=(u16*)(ws+o_S); u16* aoh=(u16*)(ws+o_aoh); u16* aout=(u16*)(ws+o_aout);
  u16* h2=(u16*)(ws+o_h2);
  u16* dn=(u16*)(ws+o_dn); u16* aff=(u16*)(ws+o_aff); u16* dnTb=(u16*)(ws+o_dnTb);
  u16* diff=(u16*)(ws+o_diff); u16* hact=(u16*)(ws+o_hact);

  dim3 blk(256), blk5(512);
  int NX, NY, ng;
  // ---- weight transposes f32 -> bf16 [N,K]
  transpose_pad<float><<<dim3(72,24,1),blk,0,stream>>>(w_qkv, qkvT, 768,2304,768, 0,0);
  transpose_pad<float><<<dim3(24,24,1),blk,0,stream>>>(ad_w,  adT,  768,768, 768, 0,0);
  transpose_pad<float><<<dim3(24,24,1),blk,0,stream>>>(w_proj,projT,768,768, 768, 0,0);
  transpose_pad<float><<<dim3(96,24,1),blk,0,stream>>>(fc1_w, fc1T, 768,3072,768, 0,0);
  transpose_pad<float><<<dim3(24,96,1),blk,0,stream>>>(fc2_w, fc2T, 3072,768,3072,0,0);
  transpose_pad<float><<<dim3(96,96,1),blk,0,stream>>>(d_outw,doutT,3072,3072,3072,0,0);
  // ---- attention block
  ln_rows<float><<<BNr,blk,0,stream>>>(x, ln1_g, ln1_b, hbuf, 768);
  ln_rows<u16>  <<<BNr,blk,0,stream>>>(hbuf, ad_ln_g, ad_ln_b, lnh, 768);
  ng=gpack(BNr,768,1,NX,NY);
  gemm_bt<F_RES><<<ng,blk,0,stream>>>(lnh,768,0, adT,768,0, metric,768,0,
      nullptr, hbuf,768,0, 1.f, nullptr, 1.f, BNr,768,768, NX,NY);
  gemm256<0><<<dim3(37*6),blk5,0,stream>>>(metric,768, qkvT,768, qkbuf,1536,
      nullptr, nullptr,0, nullptr,nullptr, 0.f, 1.f, BNr,1536,768, 37);
  ng=gpack(BNr,768,1,NX,NY);
  gemm_bt<0><<<ng,blk,0,stream>>>(hbuf,768,0, qkvT+(size_t)1536*768,768,0, vbuf,768,0,
      nullptr, nullptr,0,0,0.f, nullptr, 1.f, BNr,768,768, NX,NY);
  split_heads<<<3462,blk,0,stream>>>(qkbuf, qh, kh);
  make_vT<<<29184,blk,0,stream>>>(vbuf, vT);
  for(int c=0;c<6;c++){
    const u16* qc=qh+(size_t)c*32*577*64;
    const u16* kc=kh+(size_t)c*32*577*64;
    ng=gpack(577,577,32,NX,NY);
    gemm_bt<0><<<ng,blk,0,stream>>>(qc,64,(long)577*64, kc,64,(long)577*64,
        Sc,608,(long)577*608, nullptr, nullptr,0,0,0.f, nullptr, 0.125f, 577,577,64, NX,NY);
    softmax_rows<<<32*577,blk,0,stream>>>(Sc,577,608, nullptr,577, 1.f);
    ng=gpack(577,64,32,NX,NY);
    gemm_bt<0><<<ng,blk,0,stream>>>(Sc,608,(long)577*608, vT+(size_t)c*32*64*608,608,(long)64*608,
        aoh+(size_t)c*32*577*64,64,(long)577*64, nullptr, nullptr,0,0,0.f, nullptr, 1.f, 577,64,608, NX,NY);
  }
  merge_heads<<<3462,blk,0,stream>>>(aoh, aout);
  ng=gpack(BNr,768,1,NX,NY);
  gemm_bt<F_RES|F_BIAS|F_RESF32|F_OUTF32><<<ng,blk,0,stream>>>(aout,768,0, projT,768,0,
      x2,768,0, b_proj, x,768,0, 1.f, nullptr, 1.f, BNr,768,768, NX,NY);
  // ---- MLP front
  ln_rows<float><<<BNr,blk,0,stream>>>(x2, ln2_g, ln2_b, h2, 768);
  gemm256<F_BIAS><<<dim3(37*12),blk5,0,stream>>>(h2,768, fc1T,768, hid,3072,
      fc1_b, nullptr,0, nullptr,nullptr, 0.f, 1.f, BNr,3072,768, 37);
  // ---- router (on UNSCALED hid; scale fused downstream)
  row_stats<<<BNr,blk,0,stream>>>(hid, stats, 3072);
  summary_kernel<<<dim3(12,16),blk,0,stream>>>(hid, stats, r_ln_g, r_ln_b, summ);
  router_kernel<<<16,blk,0,stream>>>(summ, r_proj_w, r_proj_b, r_gate_w, r_gate_b, r_scale, scalef);
  // ---- token diffusion (dn = LN(hid*scale))
  dn_kernel<<<BNr,blk,0,stream>>>(hid, d_ln_g, d_ln_b, scalef, dn, rn);
  dgate_kernel<<<16,blk,0,stream>>>(dn, d_gate_w, d_gate_b, dgate);
  ng=gpack(577,577,16,NX,NY);
  gemm_bt<0><<<ng,blk,0,stream>>>(dn,3072,(long)577*3072, dn,3072,(long)577*3072,
      aff,608,(long)577*608, nullptr, nullptr,0,0,0.f, nullptr, 1.f, 577,577,3072, NX,NY);
  softmax_rows<<<BNr,blk,0,stream>>>(aff,577,608, rn,577, 0.01804219634f);
  for(int g4=0; g4<4; ++g4){
    transpose_pad<u16><<<dim3(96,19,4),blk,0,stream>>>(dn+(size_t)g4*4*577*3072, dnTb,
        577,3072,608, (long)577*3072, (long)3072*608);
    ng=gpack(577,3072,4,NX,NY);
    gemm_bt<F_RES><<<ng,blk,0,stream>>>(aff+(size_t)g4*4*577*608,608,(long)577*608,
        dnTb,608,(long)3072*608, diff+(size_t)g4*4*577*3072,3072,(long)577*3072,
        nullptr, dn+(size_t)g4*4*577*3072,3072,(long)577*3072, -1.f, nullptr, 1.f, 577,3072,608, NX,NY);
  }
  // dmix: hact = gelu(dgate[z]*(diff@doutT) + scale[z,cg]*hid)   (flattened M)
  gemm256<F_GELU|F_GATE|F_SCRES><<<dim3(37*12),blk5,0,stream>>>(diff,3072, doutT,3072,
      hact,3072, nullptr, hid,3072, dgate, scalef, 1.f/577.f, 1.f, BNr,3072,3072, 37);
  // ---- fc2 + final residual (f32 out)
  ng=gpack(BNr,768,1,NX,NY);
  gemm_bt<F_RES|F_BIAS|F_RESF32|F_OUTF32><<<ng,blk,0,stream>>>(hact,3072,0,
      fc2T,3072,0, d_out,768,0, fc2_b, x2,768,0, 1.f, nullptr, 1.f, BNr,768,3072, NX,NY);
}

// Round 5
// 1500.760 us; speedup vs baseline: 1.1116x; 1.0055x over previous
//
#include <hip/hip_runtime.h>
#include <math.h>

typedef unsigned short u16;
typedef unsigned int   u32;
typedef __attribute__((ext_vector_type(4))) float f32x4;
typedef __attribute__((ext_vector_type(4))) u32   u32x4;

#define DEV __device__ __forceinline__
#define AS1 __attribute__((address_space(1)))
#define AS3 __attribute__((address_space(3)))

DEV float b2f(u16 u){ u32 x = ((u32)u)<<16; float f; __builtin_memcpy(&f,&x,4); return f; }
DEV u16 f2b(float f){ u32 x; __builtin_memcpy(&x,&f,4); u32 r = x + 0x7FFFu + ((x>>16)&1u); return (u16)(r>>16); }

DEV float ldf(const float* p, long i){ return p[i]; }
DEV float ldf(const u16*   p, long i){ return b2f(p[i]); }

DEV void gload16(const u16* g, u16* l){
  __builtin_amdgcn_global_load_lds((const AS1 u32*)(const void*)g,
                                   (AS3 u32*)(void*)l, 16, 0, 0);
}

DEV float wave_sum(float v){
#pragma unroll
  for(int o=32;o;o>>=1) v += __shfl_down(v,o,64);
  return v;
}
DEV float wave_max(float v){
#pragma unroll
  for(int o=32;o;o>>=1) v = fmaxf(v, __shfl_down(v,o,64));
  return v;
}
// blockDim.x == 256 assumed in block_sum/block_max users.
DEV float block_sum(float v, float* tmp){
  v = wave_sum(v);
  if((threadIdx.x&63)==0) tmp[threadIdx.x>>6]=v;
  __syncthreads();
  float r = tmp[0]+tmp[1]+tmp[2]+tmp[3];
  __syncthreads();
  return r;
}
DEV float block_max(float v, float* tmp){
  v = wave_max(v);
  if((threadIdx.x&63)==0) tmp[threadIdx.x>>6]=v;
  __syncthreads();
  float r = fmaxf(fmaxf(tmp[0],tmp[1]),fmaxf(tmp[2],tmp[3]));
  __syncthreads();
  return r;
}

// ---------------- transpose (+K-pad with zeros), out always bf16 -------------
template<typename TI>
__global__ void transpose_pad(const TI* __restrict__ in, u16* __restrict__ out,
                              int R, int C, int Rpad, long strideI, long strideO){
  __shared__ u16 t[32][33];
  in  += (long)blockIdx.z*strideI;
  out += (long)blockIdx.z*strideO;
  int tx = threadIdx.x & 31, ty = threadIdx.x >> 5;
  int bc = blockIdx.x*32, br = blockIdx.y*32;
#pragma unroll
  for(int i=0;i<32;i+=8){
    int r = br+ty+i, c = bc+tx;
    float v = (r<R && c<C) ? ldf(in,(long)r*C+c) : 0.f;
    t[ty+i][tx] = f2b(v);
  }
  __syncthreads();
#pragma unroll
  for(int i=0;i<32;i+=8){
    int c = bc+ty+i, r = br+tx;
    if(c<C && r<Rpad) out[(long)c*Rpad + r] = t[tx][ty+i];
  }
}

// ---------------- LayerNorm rows ---------------------------------------------
template<typename TI>
__global__ void ln_rows(const TI* __restrict__ x, const float* __restrict__ g,
                        const float* __restrict__ b, u16* __restrict__ y, int W){
  __shared__ float tmp[4];
  long base=(long)blockIdx.x*W;
  float s=0.f, ss=0.f;
  for(int c=threadIdx.x;c<W;c+=256){ float v=ldf(x,base+c); s+=v; ss+=v*v; }
  s=block_sum(s,tmp); ss=block_sum(ss,tmp);
  float mu=s/W;
  float rstd=rsqrtf(fmaxf(ss/W-mu*mu,0.f)+1e-5f);
  for(int c=threadIdx.x;c<W;c+=256){
    float v=ldf(x,base+c);
    y[base+c]=f2b((v-mu)*rstd*g[c]+b[c]);
  }
}

__global__ void row_stats(const u16* __restrict__ x, float* __restrict__ stats, int W){
  __shared__ float tmp[4];
  long base=(long)blockIdx.x*W;
  float s=0.f,ss=0.f;
  for(int c=threadIdx.x;c<W;c+=256){ float v=b2f(x[base+c]); s+=v; ss+=v*v; }
  s=block_sum(s,tmp); ss=block_sum(ss,tmp);
  if(threadIdx.x==0){
    float mu=s/W;
    stats[2*(long)blockIdx.x]=mu;
    stats[2*(long)blockIdx.x+1]=rsqrtf(fmaxf(ss/W-mu*mu,0.f)+1e-5f);
  }
}

// dn = LN(hid*scale; d_ln), rn = 1/max(||dn||,1e-12)  (router scale fused in)
__global__ void dn_kernel(const u16* __restrict__ x, const float* __restrict__ g,
                          const float* __restrict__ b, const float* __restrict__ scalef,
                          u16* __restrict__ dn, float* __restrict__ rn){
  const int W=3072;
  __shared__ float tmp[4];
  __shared__ u16 rowb[3072];
  long row=(long)blockIdx.x;
  long base=row*(long)W;
  int bz=(int)(row/577);
  float s=0.f,ss=0.f;
  for(int c=threadIdx.x;c<W;c+=256){
    float sc=scalef[bz*4 + ((c>>8)/3)];
    float v=b2f(x[base+c])*sc;
    rowb[c]=f2b(v);
    s+=v; ss+=v*v;
  }
  s=block_sum(s,tmp); ss=block_sum(ss,tmp);
  float mu=s/W;
  float rstd=rsqrtf(fmaxf(ss/W-mu*mu,0.f)+1e-5f);
  float sq=0.f;
  for(int c=threadIdx.x;c<W;c+=256){
    float v=(b2f(rowb[c])-mu)*rstd*g[c]+b[c];
    sq+=v*v;
  }
  sq=block_sum(sq,tmp);
  float r=1.f/fmaxf(sqrtf(sq),1e-12f);
  for(int c=threadIdx.x;c<W;c+=256){
    float v=(b2f(rowb[c])-mu)*rstd*g[c]+b[c];
    dn[base+c]=f2b(v);
  }
  if(threadIdx.x==0) rn[blockIdx.x]=r;
}

// ------------- softmax over rows (in-place bf16), optional row/col scaling ---
__global__ void softmax_rows(u16* __restrict__ S, int W, int Wp,
                             const float* __restrict__ rs, int rpb, float alpha){
  __shared__ float tmp[4];
  long row = blockIdx.x;
  u16* p = S + row*(long)Wp;
  float rowscale = alpha;
  const float* rsb = nullptr;
  if(rs){ long bt=row/rpb; int m=(int)(row%rpb); rsb = rs + bt*(long)rpb; rowscale *= rsb[m]; }
  float mx=-3e38f;
  for(int c=threadIdx.x;c<W;c+=256){
    float v=b2f(p[c])*rowscale; if(rs) v*=rsb[c];
    mx=fmaxf(mx,v);
  }
  mx=block_max(mx,tmp);
  float sm=0.f;
  for(int c=threadIdx.x;c<W;c+=256){
    float v=b2f(p[c])*rowscale; if(rs) v*=rsb[c];
    sm+=__expf(v-mx);
  }
  sm=block_sum(sm,tmp);
  float inv=1.f/sm;
  for(int c=threadIdx.x;c<W;c+=256){
    float v=b2f(p[c])*rowscale; if(rs) v*=rsb[c];
    p[c]=f2b(__expf(v-mx)*inv);
  }
  for(int c=W+threadIdx.x;c<Wp;c+=256) p[c]=0;
}

// ---------------- attention head reshapes ------------------------------------
__global__ void split_heads(const u16* __restrict__ qk, u16* __restrict__ qh, u16* __restrict__ kh){
  int i = blockIdx.x*256+threadIdx.x;
  if(i >= 16*577*12*8) return;
  int dv = i&7; int h=(i>>3)%12; int bn=i/96;
  int b=bn/577, n=bn%577;
  long src=(long)bn*1536 + h*64 + dv*8;
  long dst=((long)((b*12+h)*577+n))*64 + dv*8;
  *(u32x4*)(qh+dst) = *(const u32x4*)(qk+src);
  *(u32x4*)(kh+dst) = *(const u32x4*)(qk+src+768);
}
__global__ void merge_heads(const u16* __restrict__ aoh, u16* __restrict__ aout){
  int i = blockIdx.x*256+threadIdx.x;
  if(i >= 16*577*12*8) return;
  int dv=i&7; int h=(i>>3)%12; int bn=i/96;
  int b=bn/577, n=bn%577;
  long dst=(long)bn*768 + h*64 + dv*8;
  long src=((long)((b*12+h)*577+n))*64 + dv*8;
  *(u32x4*)(aout+dst) = *(const u32x4*)(aoh+src);
}
__global__ void make_vT(const u16* __restrict__ v, u16* __restrict__ vT){
  long i = (long)blockIdx.x*256+threadIdx.x;
  if(i >= (long)192*64*608) return;
  int n=(int)(i%608); long q=i/608; int d=(int)(q&63); int bh=(int)(q>>6);
  int b=bh/12, h=bh%12;
  u16 val=0;
  if(n<577) val = v[((long)(b*577+n))*768 + h*64 + d];
  vT[i]=val;
}

// ---------------- router -----------------------------------------------------
__global__ void summary_kernel(const u16* __restrict__ hid, const float* __restrict__ stats,
                               const float* __restrict__ rg, const float* __restrict__ rb,
                               float* __restrict__ summ){
  int b=blockIdx.y;
  int c=blockIdx.x*256+threadIdx.x;   // grid.x=12 -> c<3072
  const u16* hb=hid+(size_t)b*577*3072;
  const float* st=stats+(size_t)b*577*2;
  float g=rg[c], be=rb[c];
  float cls=(b2f(hb[c])-st[0])*st[1]*g+be;
  float acc=0.f;
  for(int n=1;n<577;n++) acc += (b2f(hb[(size_t)n*3072+c])-st[2*n])*st[2*n+1];
  summ[(size_t)b*6144+c]        = 1.0f*cls;                         // CLS_MIX
  summ[(size_t)b*6144+3072+c]   = 0.5f*(g*(acc*(1.f/576.f))+be);    // MEAN_MIX
}

__global__ void router_kernel(const float* __restrict__ summ, const float* __restrict__ pw,
                              const float* __restrict__ pb, const float* __restrict__ gw,
                              const float* __restrict__ gb, const float* __restrict__ rsc,
                              float* __restrict__ scalef){
  __shared__ float tmp[4];
  int b=blockIdx.x;
  float a0=0,a1=0,a2=0,a3=0,a4=0;
  for(int c=threadIdx.x;c<6144;c+=256){
    float sv=summ[(size_t)b*6144+c];
    a0+=sv*pw[c*4+0]; a1+=sv*pw[c*4+1]; a2+=sv*pw[c*4+2]; a3+=sv*pw[c*4+3];
    a4+=sv*gw[c];
  }
  a0=block_sum(a0,tmp); a1=block_sum(a1,tmp); a2=block_sum(a2,tmp);
  a3=block_sum(a3,tmp); a4=block_sum(a4,tmp);
  if(threadIdx.x==0){
    float l0=a0+pb[0], l1=a1+pb[1], l2=a2+pb[2], l3=a3+pb[3];
    float mx=fmaxf(fmaxf(l0,l1),fmaxf(l2,l3));
    float e0=__expf(l0-mx),e1=__expf(l1-mx),e2=__expf(l2-mx),e3=__expf(l3-mx);
    float s=e0+e1+e2+e3;
    float gate=1.f/(1.f+__expf(-(a4+gb[0])));
    float w0=e0/s,w1=e1/s,w2=e2/s,w3=e3/s;
    scalef[b*4+0]=1.f+gate*rsc[0]*(4.f*w0-1.f);
    scalef[b*4+1]=1.f+gate*rsc[1]*(4.f*w1-1.f);
    scalef[b*4+2]=1.f+gate*rsc[2]*(4.f*w2-1.f);
    scalef[b*4+3]=1.f+gate*rsc[3]*(4.f*w3-1.f);
  }
}

__global__ void dgate_kernel(const u16* __restrict__ dn, const float* __restrict__ gw,
                             const float* __restrict__ gb, float* __restrict__ dgate){
  __shared__ float tmp[4];
  int b=blockIdx.x;
  const u16* row = dn + (size_t)b*577*3072;
  float a=0.f;
  for(int c=threadIdx.x;c<3072;c+=256) a+=b2f(row[c])*gw[c];
  a=block_sum(a,tmp);
  if(threadIdx.x==0) dgate[b]=1.f/(1.f+__expf(-(a+gb[0])));
}

constexpr int F_BIAS=1, F_RES=2, F_GELU=4, F_GATE=8, F_RESF32=16, F_OUTF32=32, F_SCRES=64;

// ---------------- 128x128 batched GEMM (small/batched shapes) ----------------
// grid decode: by (N-tile) FASTEST -> XCD chunks share A-panels (bx bands).
DEV int swz(int u){ int row=u>>2, sl=u&3; return row*4 + (sl ^ ((row>>1)&3)); }

template<int FLAGS>
__global__ __launch_bounds__(256,2) void gemm_bt(
  const u16* __restrict__ A, long lda, long szA,
  const u16* __restrict__ B, long ldb, long szB,
  void* __restrict__ Cv, long ldc, long szC,
  const float* __restrict__ bias,
  const void* __restrict__ resv, long ldr, long szR, float res_scale,
  const float* __restrict__ gate,
  float alpha, int M, int N, int K, int NX, int NY)
{
  __shared__ alignas(16) u16 shA[128*32];
  __shared__ alignas(16) u16 shB[128*32];
  const int nwg = (int)gridDim.x;
  const int orig = (int)blockIdx.x;
  const int q = nwg>>3, r = nwg&7;
  const int xcd = orig&7, idx = orig>>3;
  const int wg = (xcd<r ? xcd*(q+1) : r*(q+1)+(xcd-r)*q) + idx;
  const int by = wg % NY; const int t_ = wg / NY;
  const int bx = t_ % NX; const int z  = t_ / NX;

  A += (long)z*szA; B += (long)z*szB;
  const int tid=threadIdx.x, lane=tid&63, wid=tid>>6;
  const int wr=wid>>1, wc=wid&1;
  const long m0=(long)bx*128, n0=(long)by*128;
  f32x4 acc[4][4];
#pragma unroll
  for(int i=0;i<4;i++)
#pragma unroll
    for(int j=0;j<4;j++){ f32x4 zv={0.f,0.f,0.f,0.f}; acc[i][j]=zv; }

  const int lr = lane>>2, lsl = lane&3;
  const u16* pA[2]; const u16* pB[2]; u16* lA[2]; u16* lB[2];
#pragma unroll
  for(int i=0;i<2;i++){
    int ra = wid*32 + i*16 + lr;
    int kc = (lsl ^ ((ra>>1)&3))*8;
    long gr = m0+ra; if(gr>=M) gr=M-1;
    long gb = n0+ra; if(gb>=N) gb=N-1;
    pA[i] = A + gr*lda + kc;
    pB[i] = B + gb*ldb + kc;
    lA[i] = shA + (wid*32 + i*16)*32;
    lB[i] = shB + (wid*32 + i*16)*32;
  }

  for(int k0=0;k0<K;k0+=32){
    __syncthreads();
#pragma unroll
    for(int i=0;i<2;i++){
      gload16(pA[i]+k0, lA[i]);
      gload16(pB[i]+k0, lB[i]);
    }
    __syncthreads();
    const int ks = lane>>4, rr = lane&15;
    u32x4 av[4], bv[4];
#pragma unroll
    for(int mi=0;mi<4;mi++) av[mi] = ((const u32x4*)shA)[swz((wr*64+mi*16+rr)*4+ks)];
#pragma unroll
    for(int ni=0;ni<4;ni++) bv[ni] = ((const u32x4*)shB)[swz((wc*64+ni*16+rr)*4+ks)];
#pragma unroll
    for(int mi=0;mi<4;mi++)
#pragma unroll
      for(int ni=0;ni<4;ni++)
        asm volatile("v_mfma_f32_16x16x32_bf16 %0, %1, %2, %0"
                     : "+v"(acc[mi][ni]) : "v"(av[mi]), "v"(bv[ni]));
  }
  const float* resf = (const float*)resv + (long)z*szR;
  const u16*   resh = (const u16*)resv   + (long)z*szR;
  float* Cf = (float*)Cv + (long)z*szC;
  u16*   Ch = (u16*)Cv   + (long)z*szC;
  float gv = (FLAGS&F_GATE)? gate[z] : 1.f;
#pragma unroll
  for(int mi=0;mi<4;mi++){
#pragma unroll
    for(int ni=0;ni<4;ni++){
      long c0 = n0 + wc*64 + ni*16 + (lane&15);
      if(c0>=N) continue;
      float bb = (FLAGS&F_BIAS)? bias[c0] : 0.f;
#pragma unroll
      for(int r2=0;r2<4;r2++){
        long rw = m0 + wr*64 + mi*16 + (lane>>4)*4 + r2;
        if(rw>=M) continue;
        float t = acc[mi][ni][r2]*alpha*gv + bb;
        if(FLAGS&F_RES){
          float rvv = (FLAGS&F_RESF32)? resf[rw*ldr+c0] : b2f(resh[rw*ldr+c0]);
          t += res_scale*rvv;
        }
        if(FLAGS&F_GELU) t = 0.5f*t*(1.f+erff(t*0.70710678118654752f));
        if(FLAGS&F_OUTF32) Cf[rw*ldc+c0]=t;
        else               Ch[rw*ldc+c0]=f2b(t);
      }
    }
  }
}

static inline int gpack(int M,int N,int nb,int& NX,int& NY){
  NX=(M+127)/128; NY=(N+127)/128; return NX*NY*nb;
}

// ---------------- 256x256 8-phase GEMM, N%256==0, K%64==0, NT>=2 -------------
// 512 thr = 8 waves (2M x 4N). BK=64. LDS 128KB = 2buf x {A,B} x 2 row-halves
// x [128 rows][8 slots][16B], slot swizzle phys = s ^ (row&7), staged linearly
// via pre-swizzled GLOBAL source. Per K-tile 4 phases:
//  p1: stage A(t+1)->nxt (4 ops) | read all B + A mh0 kk0 | BAR | MFMA | BAR
//  p2: read A mh1 kk0 | BAR | MFMA | BAR
//  p3: stage B0(t+2)->cur | read A mh0 kk1 | BAR | MFMA | BAR
//  p4: stage B1(t+2)->cur | read A mh1 kk1 | vmcnt(4) | BAR | MFMA | BAR
// No phase stages a region it reads (B(t) fully read at p1; A(t+1) goes to nxt).
// vmcnt(4) leaves only B(t+2) outstanding => A(t+1),B(t+1) resident. Grid decode
// by-fastest: XCD chunk = contiguous bx band x all by  => A fetched once chipwide.
template<int FLAGS>
__global__ __launch_bounds__(512,2) void gemm256(
  const u16* __restrict__ A, long lda,
  const u16* __restrict__ B, long ldb,
  void* __restrict__ Cv, long ldc,
  const float* __restrict__ bias,
  const void* __restrict__ resv, long ldr,
  const float* __restrict__ gate, const float* __restrict__ scres,
  float irpz, float alpha, int M, int N, int K, int NY)
{
  __shared__ alignas(16) u16 smem[65536];
  char* sm=(char*)smem;
  const int nwg=(int)gridDim.x, orig=(int)blockIdx.x;
  const int qq=nwg>>3, rr8=nwg&7, xcd=orig&7, idx=orig>>3;
  const int wg=(xcd<rr8? xcd*(qq+1): rr8*(qq+1)+(xcd-rr8)*qq)+idx;
  const int by=wg%NY, bx=wg/NY;
  const long m0=(long)bx*256, n0=(long)by*256;
  const int tid=threadIdx.x, lane=tid&63, wid=tid>>6;
  const int wr=wid>>2, wc=wid&3, l15=lane&15, ks=lane>>4;

  f32x4 acc[8][4];
#pragma unroll
  for(int i=0;i<8;i++)
#pragma unroll
    for(int j=0;j<4;j++){ f32x4 zv={0.f,0.f,0.f,0.f}; acc[i][j]=zv; }

  // staging sources (k-invariant, pre-swizzled cols), linear LDS dests
  const u16 *sA[2][2], *sB[2][2];   // [half][j]
  int dstj[2];
#pragma unroll
  for(int j=0;j<2;j++){
    int u=j*512+tid, row=u>>3;
    long co=(long)(((u&7)^(row&7))*8);
    dstj[j]=u*16;
#pragma unroll
    for(int h=0;h<2;h++){
      long gr=m0+h*128+row; if(gr>=M) gr=M-1;
      long gb=n0+h*128+row; if(gb>=N) gb=N-1;
      sA[h][j]=A+gr*lda+co;
      sB[h][j]=B+gb*ldb+co;
    }
  }
  // ds_read bases (bytes within one 64KB buffer)
  int xsl[2]; xsl[0]=((ks^(l15&7))<<4); xsl[1]=(((4+ks)^(l15&7))<<4);
  const int arow = wr*16384 + l15*128;                 // A at offset 0
  int brow[4];
#pragma unroll
  for(int nj=0;nj<4;nj++){ int n=wc*64+nj*16; brow[nj]=32768+(n>>7)*16384+((n&127)+l15)*128; }
  const int NT=K>>6;

#define STG(P,mat,h,kt,bf) { \
  gload16(P[h][0]+(long)(kt)*64,(u16*)(sm+(bf)*65536+(mat)*32768+(h)*16384+dstj[0])); \
  gload16(P[h][1]+(long)(kt)*64,(u16*)(sm+(bf)*65536+(mat)*32768+(h)*16384+dstj[1])); }
#define BAR() { asm volatile("":::"memory"); __builtin_amdgcn_s_barrier(); asm volatile("":::"memory"); }
#define MFMA16(A0,KB) { \
  __builtin_amdgcn_s_setprio(1); \
  _Pragma("unroll") for(int i_=0;i_<4;i_++) \
  _Pragma("unroll") for(int j_=0;j_<4;j_++) \
    asm volatile("v_mfma_f32_16x16x32_bf16 %0, %1, %2, %0" \
                 :"+v"(acc[(A0)+i_][j_]):"v"(av[i_]),"v"(bv[KB][j_])); \
  __builtin_amdgcn_s_setprio(0); }

  // prologue: tile0 fully -> buf0; B(1) -> buf1; vmcnt(4) retires tile0.
  STG(sA,0,0,0,0); STG(sA,0,1,0,0); STG(sB,1,0,0,0); STG(sB,1,1,0,0);
  STG(sB,1,0,1,1); STG(sB,1,1,1,1);
  asm volatile("s_waitcnt vmcnt(4)":::"memory");
  BAR();

  u32x4 av[4], bv[2][4];
  for(int t=0;t<NT;++t){
    const int cur=t&1, nxt=cur^1;
    const char* bp = sm + cur*65536;
    // phase 1
    if(t+1<NT){ STG(sA,0,0,t+1,nxt); STG(sA,0,1,t+1,nxt); }
#pragma unroll
    for(int kk=0;kk<2;kk++)
#pragma unroll
      for(int nj=0;nj<4;nj++) bv[kk][nj]=*(const u32x4*)(bp+brow[nj]+xsl[kk]);
#pragma unroll
    for(int i=0;i<4;i++) av[i]=*(const u32x4*)(bp+arow+i*2048+xsl[0]);
    BAR();
    MFMA16(0,0);
    BAR();
    // phase 2
#pragma unroll
    for(int i=0;i<4;i++) av[i]=*(const u32x4*)(bp+arow+(4+i)*2048+xsl[0]);
    BAR();
    MFMA16(4,0);
    BAR();
    // phase 3
    if(t+2<NT) STG(sB,1,0,t+2,cur);
#pragma unroll
    for(int i=0;i<4;i++) av[i]=*(const u32x4*)(bp+arow+i*2048+xsl[1]);
    BAR();
    MFMA16(0,1);
    BAR();
    // phase 4
    if(t+2<NT) STG(sB,1,1,t+2,cur);
#pragma unroll
    for(int i=0;i<4;i++) av[i]=*(const u32x4*)(bp+arow+(4+i)*2048+xsl[1]);
    if(t+2<NT) asm volatile("s_waitcnt vmcnt(4)":::"memory");
    else       asm volatile("s_waitcnt vmcnt(0)":::"memory");
    BAR();
    MFMA16(4,1);
    BAR();
  }
#undef STG
#undef BAR
#undef MFMA16

  const float* resf=(const float*)resv; const u16* resh=(const u16*)resv;
  float* Cf=(float*)Cv; u16* Ch=(u16*)Cv;
#pragma unroll
  for(int mf=0;mf<8;mf++){
#pragma unroll
    for(int j=0;j<4;j++){
      long c0 = n0 + wc*64 + j*16 + l15;
      float bb=(FLAGS&F_BIAS)? bias[c0]:0.f;
      int cg=((int)(c0>>8))/3;     // c0/768
#pragma unroll
      for(int r2=0;r2<4;r2++){
        long rw = m0 + wr*128 + mf*16 + ks*4 + r2;
        if(rw>=M) continue;
        float t=acc[mf][j][r2]*alpha;
        if(FLAGS&(F_GATE|F_SCRES)){
          int z=(int)(((float)rw+0.5f)*irpz);
          if(FLAGS&F_GATE) t*=gate[z];
          if(FLAGS&F_SCRES) t += scres[z*4+cg]*b2f(resh[rw*ldr+c0]);
        } else if(FLAGS&F_RES){
          float rvv=(FLAGS&F_RESF32)? resf[rw*ldr+c0] : b2f(resh[rw*ldr+c0]);
          t += rvv;
        }
        t+=bb;
        if(FLAGS&F_GELU) t=0.5f*t*(1.f+erff(t*0.70710678118654752f));
        if(FLAGS&F_OUTF32) Cf[rw*ldc+c0]=t;
        else               Ch[rw*ldc+c0]=f2b(t);
      }
    }
  }
}

extern "C" void kernel_launch(void* const* d_in, const int* in_sizes, int n_in,
                              void* d_out, int out_size, void* d_ws, size_t ws_size,
                              hipStream_t stream){
  const int BNr=16*577;            // 9232 rows
  const float* x      = (const float*)d_in[0];
  const float* ln1_g  = (const float*)d_in[1];
  const float* ln1_b  = (const float*)d_in[2];
  const float* ad_ln_g= (const float*)d_in[3];
  const float* ad_ln_b= (const float*)d_in[4];
  const float* ad_w   = (const float*)d_in[5];
  const float* w_qkv  = (const float*)d_in[6];
  const float* w_proj = (const float*)d_in[7];
  const float* b_proj = (const float*)d_in[8];
  const float* ln2_g  = (const float*)d_in[9];
  const float* ln2_b  = (const float*)d_in[10];
  const float* fc1_w  = (const float*)d_in[11];
  const float* fc1_b  = (const float*)d_in[12];
  const float* fc2_w  = (const float*)d_in[13];
  const float* fc2_b  = (const float*)d_in[14];
  const float* r_ln_g = (const float*)d_in[15];
  const float* r_ln_b = (const float*)d_in[16];
  const float* r_proj_w=(const float*)d_in[17];
  const float* r_proj_b=(const float*)d_in[18];
  const float* r_gate_w=(const float*)d_in[19];
  const float* r_gate_b=(const float*)d_in[20];
  const float* r_scale =(const float*)d_in[21];
  const float* d_ln_g = (const float*)d_in[22];
  const float* d_ln_b = (const float*)d_in[23];
  const float* d_outw = (const float*)d_in[24];
  const float* d_gate_w=(const float*)d_in[25];
  const float* d_gate_b=(const float*)d_in[26];

  char* ws=(char*)d_ws;
  size_t off=0;
  auto take=[&](size_t nb){ size_t r=off; off=(off+nb+255)&~(size_t)255; return r; };
  auto al  =[&](size_t v){ return (v+255)&~(size_t)255; };
  const size_t o_qkvT = take((size_t)2304*768*2);
  const size_t o_adT  = take((size_t)768*768*2);
  const size_t o_projT= take((size_t)768*768*2);
  const size_t o_fc1T = take((size_t)3072*768*2);
  const size_t o_fc2T = take((size_t)768*3072*2);
  const size_t o_doutT= take((size_t)3072*3072*2);
  const size_t o_x2   = take((size_t)BNr*768*4);       // f32
  const size_t o_hid  = take((size_t)BNr*3072*2);
  const size_t o_stats= take((size_t)BNr*2*4);
  const size_t o_rn   = take((size_t)BNr*4);
  const size_t o_sum  = take((size_t)16*6144*4);
  const size_t o_scalef=take(64*4);
  const size_t o_dg   = take(64);
  const size_t o_h    = take((size_t)BNr*768*2);
  const size_t o_lnh  = take((size_t)BNr*768*2);
  const size_t o_metric=take((size_t)BNr*768*2);
  const size_t o_qk   = take((size_t)BNr*1536*2);
  const size_t o_v    = take((size_t)BNr*768*2);
  const size_t o_qh   = take((size_t)192*577*64*2);
  const size_t o_kh   = take((size_t)192*577*64*2);
  const size_t o_vT   = take((size_t)192*64*608*2);
  (void)o_v; (void)o_vT; (void)ws_size; (void)in_sizes; (void)n_in; (void)out_size;
  const size_t o_S    = o_qk;
  const size_t o_aoh  = o_metric;
  const size_t o_aout = o_h;
  const size_t o_h2   = o_lnh;
  const size_t o_dn   = o_h;
  const size_t o_aff  = al(o_dn + (size_t)BNr*3072*2);
  const size_t o_dnTb = al(o_aff + (size_t)16*577*608*2);
  const size_t o_diff = al(o_dnTb + (size_t)4*3072*608*2);
  const size_t o_hact = o_dn;

  u16* qkvT=(u16*)(ws+o_qkvT); u16* adT=(u16*)(ws+o_adT); u16* projT=(u16*)(ws+o_projT);
  u16* fc1T=(u16*)(ws+o_fc1T); u16* fc2T=(u16*)(ws+o_fc2T); u16* doutT=(u16*)(ws+o_doutT);
  float* x2=(float*)(ws+o_x2); u16* hid=(u16*)(ws+o_hid);
  float* stats=(float*)(ws+o_stats); float* rn=(float*)(ws+o_rn);
  float* summ=(float*)(ws+o_sum); float* scalef=(float*)(ws+o_scalef); float* dgate=(float*)(ws+o_dg);
  u16* hbuf=(u16*)(ws+o_h); u16* lnh=(u16*)(ws+o_lnh); u16* metric=(u16*)(ws+o_metric);
  u16* qkbuf=(u16*)(ws+o_qk); u16* vbuf=(u16*)(ws+o_v);
  u16* qh=(u16*)(ws+o_qh); u16* kh=(u16*)(ws+o_kh); u16* vT=(u16*)(ws+o_vT);
  u16* Sc=(u16*)(ws+o_S); u16* aoh=(u16*)(ws+o_aoh); u16* aout=(u16*)(ws+o_aout);
  u16* h2=(u16*)(ws+o_h2);
  u16* dn=(u16*)(ws+o_dn); u16* aff=(u16*)(ws+o_aff); u16* dnTb=(u16*)(ws+o_dnTb);
  u16* diff=(u16*)(ws+o_diff); u16* hact=(u16*)(ws+o_hact);

  dim3 blk(256), blk5(512);
  int NX, NY, ng;
  // ---- weight transposes f32 -> bf16 [N,K]
  transpose_pad<float><<<dim3(72,24,1),blk,0,stream>>>(w_qkv, qkvT, 768,2304,768, 0,0);
  transpose_pad<float><<<dim3(24,24,1),blk,0,stream>>>(ad_w,  adT,  768,768, 768, 0,0);
  transpose_pad<float><<<dim3(24,24,1),blk,0,stream>>>(w_proj,projT,768,768, 768, 0,0);
  transpose_pad<float><<<dim3(96,24,1),blk,0,stream>>>(fc1_w, fc1T, 768,3072,768, 0,0);
  transpose_pad<float><<<dim3(24,96,1),blk,0,stream>>>(fc2_w, fc2T, 3072,768,3072,0,0);
  transpose_pad<float><<<dim3(96,96,1),blk,0,stream>>>(d_outw,doutT,3072,3072,3072,0,0);
  // ---- attention block
  ln_rows<float><<<BNr,blk,0,stream>>>(x, ln1_g, ln1_b, hbuf, 768);
  ln_rows<u16>  <<<BNr,blk,0,stream>>>(hbuf, ad_ln_g, ad_ln_b, lnh, 768);
  ng=gpack(BNr,768,1,NX,NY);
  gemm_bt<F_RES><<<ng,blk,0,stream>>>(lnh,768,0, adT,768,0, metric,768,0,
      nullptr, hbuf,768,0, 1.f, nullptr, 1.f, BNr,768,768, NX,NY);
  gemm256<0><<<dim3(37*6),blk5,0,stream>>>(metric,768, qkvT,768, qkbuf,1536,
      nullptr, nullptr,0, nullptr,nullptr, 0.f, 1.f, BNr,1536,768, 6);
  ng=gpack(BNr,768,1,NX,NY);
  gemm_bt<0><<<ng,blk,0,stream>>>(hbuf,768,0, qkvT+(size_t)1536*768,768,0, vbuf,768,0,
      nullptr, nullptr,0,0,0.f, nullptr, 1.f, BNr,768,768, NX,NY);
  split_heads<<<3462,blk,0,stream>>>(qkbuf, qh, kh);
  make_vT<<<29184,blk,0,stream>>>(vbuf, vT);
  for(int c=0;c<6;c++){
    const u16* qc=qh+(size_t)c*32*577*64;
    const u16* kc=kh+(size_t)c*32*577*64;
    ng=gpack(577,577,32,NX,NY);
    gemm_bt<0><<<ng,blk,0,stream>>>(qc,64,(long)577*64, kc,64,(long)577*64,
        Sc,608,(long)577*608, nullptr, nullptr,0,0,0.f, nullptr, 0.125f, 577,577,64, NX,NY);
    softmax_rows<<<32*577,blk,0,stream>>>(Sc,577,608, nullptr,577, 1.f);
    ng=gpack(577,64,32,NX,NY);
    gemm_bt<0><<<ng,blk,0,stream>>>(Sc,608,(long)577*608, vT+(size_t)c*32*64*608,608,(long)64*608,
        aoh+(size_t)c*32*577*64,64,(long)577*64, nullptr, nullptr,0,0,0.f, nullptr, 1.f, 577,64,608, NX,NY);
  }
  merge_heads<<<3462,blk,0,stream>>>(aoh, aout);
  ng=gpack(BNr,768,1,NX,NY);
  gemm_bt<F_RES|F_BIAS|F_RESF32|F_OUTF32><<<ng,blk,0,stream>>>(aout,768,0, projT,768,0,
      x2,768,0, b_proj, x,768,0, 1.f, nullptr, 1.f, BNr,768,768, NX,NY);
  // ---- MLP front
  ln_rows<float><<<BNr,blk,0,stream>>>(x2, ln2_g, ln2_b, h2, 768);
  gemm256<F_BIAS><<<dim3(37*12),blk5,0,stream>>>(h2,768, fc1T,768, hid,3072,
      fc1_b, nullptr,0, nullptr,nullptr, 0.f, 1.f, BNr,3072,768, 12);
  // ---- router (on UNSCALED hid; scale fused downstream)
  row_stats<<<BNr,blk,0,stream>>>(hid, stats, 3072);
  summary_kernel<<<dim3(12,16),blk,0,stream>>>(hid, stats, r_ln_g, r_ln_b, summ);
  router_kernel<<<16,blk,0,stream>>>(summ, r_proj_w, r_proj_b, r_gate_w, r_gate_b, r_scale, scalef);
  // ---- token diffusion (dn = LN(hid*scale))
  dn_kernel<<<BNr,blk,0,stream>>>(hid, d_ln_g, d_ln_b, scalef, dn, rn);
  dgate_kernel<<<16,blk,0,stream>>>(dn, d_gate_w, d_gate_b, dgate);
  ng=gpack(577,577,16,NX,NY);
  gemm_bt<0><<<ng,blk,0,stream>>>(dn,3072,(long)577*3072, dn,3072,(long)577*3072,
      aff,608,(long)577*608, nullptr, nullptr,0,0,0.f, nullptr, 1.f, 577,577,3072, NX,NY);
  softmax_rows<<<BNr,blk,0,stream>>>(aff,577,608, rn,577, 0.01804219634f);
  for(int g4=0; g4<4; ++g4){
    transpose_pad<u16><<<dim3(96,19,4),blk,0,stream>>>(dn+(size_t)g4*4*577*3072, dnTb,
        577,3072,608, (long)577*3072, (long)3072*608);
    ng=gpack(577,3072,4,NX,NY);
    gemm_bt<F_RES><<<ng,blk,0,stream>>>(aff+(size_t)g4*4*577*608,608,(long)577*608,
        dnTb,608,(long)3072*608, diff+(size_t)g4*4*577*3072,3072,(long)577*3072,
        nullptr, dn+(size_t)g4*4*577*3072,3072,(long)577*3072, -1.f, nullptr, 1.f, 577,3072,608, NX,NY);
  }
  // dmix: hact = gelu(dgate[z]*(diff@doutT) + scale[z,cg]*hid)   (flattened M)
  gemm256<F_GELU|F_GATE|F_SCRES><<<dim3(37*12),blk5,0,stream>>>(diff,3072, doutT,3072,
      hact,3072, nullptr, hid,3072, dgate, scalef, 1.f/577.f, 1.f, BNr,3072,3072, 12);
  // ---- fc2 + final residual (f32 out)
  ng=gpack(BNr,768,1,NX,NY);
  gemm_bt<F_RES|F_BIAS|F_RESF32|F_OUTF32><<<ng,blk,0,stream>>>(hact,3072,0,
      fc2T,3072,0, d_out,768,0, fc2_b, x2,768,0, 1.f, nullptr, 1.f, BNr,768,3072, NX,NY);
}